// Round 8
// baseline (396.586 us; speedup 1.0000x reference)
//
#include <hip/hip_runtime.h>
#include <math.h>

#define N_NODES 50000
#define N_EDGES 800000
#define HEADS 4
#define HID 64
#define FDIM 256      // HEADS*HID == F_IN == 256 for both layers
#define LDA 40        // padded LDS k-stride (halves): 80B row stride

typedef __attribute__((ext_vector_type(8))) _Float16 half8;
typedef __attribute__((ext_vector_type(4))) _Float16 half4;
typedef __attribute__((ext_vector_type(4))) float f32x4;

// ---------------------------------------------------------------- prep
// Fused: zero counts+cursor (blocks 32..47) + W transpose-cast (blocks
// 0..31). Independent outputs -> no sync needed. Replaces memset + wcast.
// (R6 lesson: grid.sync() costs ~100us/sync on MI355X — fuse only
// independent work; keep dependent phases as separate dispatches.)
__global__ __launch_bounds__(256) void prep_kernel(const float* __restrict__ W0,
                                                   const float* __restrict__ W1,
                                                   _Float16* __restrict__ wt0,
                                                   _Float16* __restrict__ wt1,
                                                   int* __restrict__ counts) {
    const int b = blockIdx.x, t = threadIdx.x;
    if (b < 32) {
        const float* W = (b >= 16) ? W1 : W0;
        _Float16* wt = (b >= 16) ? wt1 : wt0;
        int n = (b & 15) * 16 + (t >> 4);
        int k0 = (t & 15) * 16;
        for (int j = 0; j < 16; j++)
            wt[n * FDIM + k0 + j] = (_Float16)W[(k0 + j) * FDIM + n];
    } else {
        // counts and cursor are contiguous: 2*N_NODES ints = 25000 int4
        int4* p = (int4*)counts;
        int4 z = make_int4(0, 0, 0, 0);
        for (int i = (b - 32) * 256 + t; i < 2 * N_NODES / 4; i += 16 * 256)
            p[i] = z;
    }
}

// ---------------------------------------------------------------- CSR build

__global__ __launch_bounds__(256) void hist_kernel(const int* __restrict__ dst,
                                                   int* __restrict__ counts, int E) {
    int i = blockIdx.x * blockDim.x + threadIdx.x;
    if (i < E) atomicAdd(&counts[dst[i]], 1);
}

// Single-block chained scan over counts[0..n) -> exclusive offsets offs[0..n].
// 1024 threads = 16 waves; per 4096-chunk: thread does 4 elems serially,
// wave-shuffle inclusive scan (no barriers), 16 wave sums scanned by wave 0.
// 13 chunks, ~4 barriers each. Replaces scan_local + scan_bsum + scan_add.
__global__ __launch_bounds__(1024) void scan_one(const int* __restrict__ counts,
                                                 int* __restrict__ offs, int n) {
    __shared__ int wsum[16];
    __shared__ int chunk_base;
    const int t = threadIdx.x;
    const int w = t >> 6, l = t & 63;
    if (t == 0) chunk_base = 0;
    __syncthreads();
    for (int c0 = 0; c0 < n; c0 += 4096) {
        int base = c0 + t * 4;
        int v[4];
#pragma unroll
        for (int j = 0; j < 4; j++) {
            int idx = base + j;
            v[j] = (idx < n) ? counts[idx] : 0;
        }
        int s = v[0] + v[1] + v[2] + v[3];
        // wave inclusive scan of s
        int ps = s;
        for (int off = 1; off < 64; off <<= 1) {
            int x = __shfl_up(ps, off);
            if (l >= off) ps += x;
        }
        if (l == 63) wsum[w] = ps;
        __syncthreads();
        if (w == 0 && l < 16) {
            int x = wsum[l];
            for (int off = 1; off < 16; off <<= 1) {
                int y = __shfl_up(x, off);
                if (l >= off) x += y;
            }
            wsum[l] = x;
        }
        __syncthreads();
        int wbase = (w > 0) ? wsum[w - 1] : 0;
        int excl = chunk_base + wbase + (ps - s);
        int e[4] = {excl, excl + v[0], excl + v[0] + v[1], excl + v[0] + v[1] + v[2]};
#pragma unroll
        for (int j = 0; j < 4; j++) {
            int idx = base + j;
            if (idx < n) offs[idx] = e[j];
        }
        __syncthreads();                       // all reads of chunk_base/wsum done
        if (t == 0) chunk_base += wsum[15];
        __syncthreads();                       // visible for next chunk
    }
    if (t == 0) offs[n] = chunk_base;          // grand total
}

__global__ __launch_bounds__(256) void scatter_kernel(const int* __restrict__ src,
                                                      const int* __restrict__ dst,
                                                      const int* __restrict__ offs,
                                                      int* __restrict__ cursor,
                                                      int* __restrict__ csr_src, int E) {
    int i = blockIdx.x * blockDim.x + threadIdx.x;
    if (i < E) {
        int d = dst[i];
        int p = offs[d] + atomicAdd(&cursor[d], 1);
        csr_src[p] = src[i];
    }
}

// -------------------------------------------- fp16 MFMA GEMM + fused el/er
// v5: operand-SWAPPED mfma — acc[mt][nt] = mfma(bf[nt], af[mt], ...) puts
// the C fragment in transposed lane order: lane's l16 = m-row, quad*4+r =
// 4 CONSECUTIVE n-cols -> 8B vector stores, el/er via per-lane float4 FMA
// + 2 shuffles. BN=256 (whole N per block), 512 threads / 8 waves, 64x64
// per wave. Template A32: stage A directly from fp32 (layer 1).
template <int A32>
__global__ __launch_bounds__(512) void mfma_gemm(const _Float16* __restrict__ A16,
                                                 const float* __restrict__ Af,
                                                 const _Float16* __restrict__ Bt,
                                                 const float* __restrict__ al,
                                                 const float* __restrict__ ar,
                                                 _Float16* __restrict__ feat16,
                                                 float* __restrict__ el,
                                                 float* __restrict__ er) {
    __shared__ _Float16 ash[128][LDA];
    __shared__ _Float16 bsh[256][LDA];

    const int t = threadIdx.x;
    const int m0 = blockIdx.x * 128;
    const int wave = t >> 6, lane = t & 63;
    const int quad = lane >> 4, l16 = lane & 15;
    const int wr = (wave >> 2) * 64;
    const int wc = (wave & 3) * 64;

    const f32x4 zero = {0.f, 0.f, 0.f, 0.f};
    f32x4 acc[4][4];
#pragma unroll
    for (int i = 0; i < 4; i++)
#pragma unroll
        for (int j = 0; j < 4; j++) acc[i][j] = zero;

    for (int kk = 0; kk < FDIM; kk += 32) {
        // ---- stage A: 128 rows x 32 halves = 512 x 8-half chunks, 1/thread
        {
            int row = t >> 2;
            int kb = (t & 3) * 8;
            int gr = m0 + row; if (gr >= N_NODES) gr = N_NODES - 1;
            if (A32) {
                const float* p = &Af[(size_t)gr * FDIM + kk + kb];
                float4 f0 = *(const float4*)p;
                float4 f1 = *(const float4*)(p + 4);
                half8 hv = {(_Float16)f0.x, (_Float16)f0.y, (_Float16)f0.z, (_Float16)f0.w,
                            (_Float16)f1.x, (_Float16)f1.y, (_Float16)f1.z, (_Float16)f1.w};
                *(half8*)&ash[row][kb] = hv;
            } else {
                *(half8*)&ash[row][kb] = *(const half8*)&A16[(size_t)gr * FDIM + kk + kb];
            }
        }
        // ---- stage B: 256 rows x 32 halves = 1024 chunks, 2/thread
#pragma unroll
        for (int ii = 0; ii < 2; ii++) {
            int idx = t + ii * 512;
            int row = idx >> 2;
            int kb = (idx & 3) * 8;
            *(half8*)&bsh[row][kb] = *(const half8*)&Bt[(size_t)row * FDIM + kk + kb];
        }
        __syncthreads();

        half8 af[4], bf[4];
#pragma unroll
        for (int i = 0; i < 4; i++) {
            af[i] = *(half8*)&ash[wr + i * 16 + l16][quad * 8];
            bf[i] = *(half8*)&bsh[wc + i * 16 + l16][quad * 8];
        }
        // swapped operands: C fragment transposed (l16 = m-row, quad*4+r = n-col)
#pragma unroll
        for (int mt = 0; mt < 4; mt++)
#pragma unroll
            for (int nt = 0; nt < 4; nt++)
                acc[mt][nt] = __builtin_amdgcn_mfma_f32_16x16x32_f16(bf[nt], af[mt], acc[mt][nt], 0, 0, 0);
        __syncthreads();
    }

    // ---- epilogue: vector feat16 store + fused el/er (this wave's head = h)
    const int h = wc >> 6;
    float4 alv[4], arv[4];
#pragma unroll
    for (int nt = 0; nt < 4; nt++) {
        alv[nt] = *(const float4*)&al[wc + nt * 16 + quad * 4];
        arv[nt] = *(const float4*)&ar[wc + nt * 16 + quad * 4];
    }
#pragma unroll
    for (int mt = 0; mt < 4; mt++) {
        const int m = m0 + wr + mt * 16 + l16;
        const bool ok = (m < N_NODES);
        float pl = 0.f, pr = 0.f;
#pragma unroll
        for (int nt = 0; nt < 4; nt++) {
            f32x4 v = acc[mt][nt];
            if (ok) {
                half4 hv = {(_Float16)v[0], (_Float16)v[1], (_Float16)v[2], (_Float16)v[3]};
                *(half4*)&feat16[(size_t)m * FDIM + wc + nt * 16 + quad * 4] = hv;
            }
            pl += v[0] * alv[nt].x + v[1] * alv[nt].y + v[2] * alv[nt].z + v[3] * alv[nt].w;
            pr += v[0] * arv[nt].x + v[1] * arv[nt].y + v[2] * arv[nt].z + v[3] * arv[nt].w;
        }
        // reduce over the 4 quads (lanes l16, l16+16, l16+32, l16+48)
        pl += __shfl_xor(pl, 16);
        pl += __shfl_xor(pl, 32);
        pr += __shfl_xor(pr, 16);
        pr += __shfl_xor(pr, 32);
        if (quad == 0 && ok) {
            el[m * 4 + h] = pl;
            er[m * 4 + h] = pr;
        }
    }
}

// ------------------------------------------- fused softmax + aggregate
// Wave per node, NO LDS / NO barriers. Lane owns features f=lane*4..+3
// (head = lane>>4).
//
// v2 (best measured; traffic-bound at ~3.9 TB/s beyond-L2, invariant to
// scheduling): cooperative weights. Edges walked in 16-chunks; W-phase:
// lane (lane&15)==j computes edge c+j's weight for its OWN head;
// MAC-phase broadcasts (s,w) via __shfl, 4-wide. Denominator accumulated
// per-lane, reduced once at the end. Single-pass softmax.
// mode 0: write h1 as fp16 (layer-2 GEMM input, lives in d_out)
// mode 1: final fp32 head-major write
__global__ __launch_bounds__(256) void agg_fused(const _Float16* __restrict__ feat16,
                                                 const float* __restrict__ el,
                                                 const float* __restrict__ er,
                                                 const float* __restrict__ bias,
                                                 const int* __restrict__ offs,
                                                 const int* __restrict__ csr_src,
                                                 float* __restrict__ out,
                                                 _Float16* __restrict__ h1,
                                                 int mode) {
    const int wave = threadIdx.x >> 6;
    const int lane = threadIdx.x & 63;
    const int n = blockIdx.x * 4 + wave;
    const int head = lane >> 4;
    const int f = lane * 4;           // == head*64 + (lane&15)*4
    const int base16 = lane & 48;     // first lane of this head's 16-group
    const int j16 = lane & 15;
    const int beg = offs[n];
    const int end = offs[n + 1];
    const float er_h = er[n * 4 + head];

    float4 acc = make_float4(0.f, 0.f, 0.f, 0.f);
    float ss = 0.f;

    for (int c = beg; c < end; c += 16) {
        // ---- W-phase: this lane owns edge c + j16 (for its own head)
        int e = c + j16;
        int s_own = 0;
        float w_own = 0.f;
        if (e < end) {
            s_own = csr_src[e];
            float lg = el[s_own * 4 + head] + er_h;
            lg = (lg > 0.f) ? lg : 0.2f * lg;
            w_own = __expf(lg);
        }
        ss += w_own;

        int rem = end - c;
        if (rem > 16) rem = 16;

        // ---- MAC-phase: walk the chunk's edges, s/w via shuffle broadcast
        int j = 0;
        for (; j + 3 < rem; j += 4) {
            int s0 = __shfl(s_own, base16 + j);
            int s1 = __shfl(s_own, base16 + j + 1);
            int s2 = __shfl(s_own, base16 + j + 2);
            int s3 = __shfl(s_own, base16 + j + 3);
            float w0 = __shfl(w_own, base16 + j);
            float w1 = __shfl(w_own, base16 + j + 1);
            float w2 = __shfl(w_own, base16 + j + 2);
            float w3 = __shfl(w_own, base16 + j + 3);
            half4 v0 = *(const half4*)&feat16[(size_t)s0 * FDIM + f];
            half4 v1 = *(const half4*)&feat16[(size_t)s1 * FDIM + f];
            half4 v2 = *(const half4*)&feat16[(size_t)s2 * FDIM + f];
            half4 v3 = *(const half4*)&feat16[(size_t)s3 * FDIM + f];
            acc.x += w0 * (float)v0[0] + w1 * (float)v1[0];
            acc.y += w0 * (float)v0[1] + w1 * (float)v1[1];
            acc.z += w0 * (float)v0[2] + w1 * (float)v1[2];
            acc.w += w0 * (float)v0[3] + w1 * (float)v1[3];
            acc.x += w2 * (float)v2[0] + w3 * (float)v3[0];
            acc.y += w2 * (float)v2[1] + w3 * (float)v3[1];
            acc.z += w2 * (float)v2[2] + w3 * (float)v3[2];
            acc.w += w2 * (float)v2[3] + w3 * (float)v3[3];
        }
        for (; j < rem; j++) {
            int s0 = __shfl(s_own, base16 + j);
            float w0 = __shfl(w_own, base16 + j);
            half4 v0 = *(const half4*)&feat16[(size_t)s0 * FDIM + f];
            acc.x += w0 * (float)v0[0];
            acc.y += w0 * (float)v0[1];
            acc.z += w0 * (float)v0[2];
            acc.w += w0 * (float)v0[3];
        }
    }

    // ---- reduce softmax denominator across the 16-lane head group
    ss += __shfl_xor(ss, 1, 16);
    ss += __shfl_xor(ss, 2, 16);
    ss += __shfl_xor(ss, 4, 16);
    ss += __shfl_xor(ss, 8, 16);

    float S = fmaxf(ss, 1e-9f);
    float inv = 1.f / S;
    float4 bv = *(const float4*)&bias[f];
    float r0 = acc.x * inv + bv.x;
    float r1 = acc.y * inv + bv.y;
    float r2 = acc.z * inv + bv.z;
    float r3 = acc.w * inv + bv.w;
    r0 = (r0 > 0.f) ? r0 : expm1f(r0);
    r1 = (r1 > 0.f) ? r1 : expm1f(r1);
    r2 = (r2 > 0.f) ? r2 : expm1f(r2);
    r3 = (r3 > 0.f) ? r3 : expm1f(r3);

    if (mode) {
        const int d = (lane & 15) * 4;
        float4 rv = make_float4(r0, r1, r2, r3);
        *(float4*)&out[(size_t)head * N_NODES * HID + (size_t)n * HID + d] = rv;
    } else {
        half4 hv = {(_Float16)r0, (_Float16)r1, (_Float16)r2, (_Float16)r3};
        *(half4*)&h1[(size_t)n * FDIM + f] = hv;
    }
}

// ---------------------------------------------------------------- launch

extern "C" void kernel_launch(void* const* d_in, const int* in_sizes, int n_in,
                              void* d_out, int out_size, void* d_ws, size_t ws_size,
                              hipStream_t stream) {
    const float* x   = (const float*)d_in[0];
    const int*   src = (const int*)d_in[1];
    const int*   dst = (const int*)d_in[2];
    const float* W0  = (const float*)d_in[3];
    const float* al0 = (const float*)d_in[4];
    const float* ar0 = (const float*)d_in[5];
    const float* b0  = (const float*)d_in[6];
    const float* W1  = (const float*)d_in[7];
    const float* al1 = (const float*)d_in[8];
    const float* ar1 = (const float*)d_in[9];
    const float* b1  = (const float*)d_in[10];
    float* out = (float*)d_out;

    // h1 (layer-1 hidden, fp16) lives in the first 25.6 MB of d_out.
    // Timeline: gemm-1 reads x fp32 directly -> agg(mode0) writes h1 ->
    // gemm-2 reads h1 -> agg(mode1) overwrites all of d_out with the final
    // output. All sequential on stream.
    _Float16* h1 = (_Float16*)d_out;

    // workspace layout
    _Float16* feat16 = (_Float16*)d_ws;                          // N*256 fp16
    _Float16* wt0 = feat16 + (size_t)N_NODES * FDIM;             // 256*256
    _Float16* wt1 = wt0 + FDIM * FDIM;                           // 256*256
    float* el    = (float*)(wt1 + FDIM * FDIM);                  // N*4
    float* er    = el + N_NODES * HEADS;                         // N*4
    int* counts  = (int*)(er + N_NODES * HEADS);                 // N
    int* cursor  = counts + N_NODES;                             // N
    int* offs    = cursor + N_NODES;                             // N+1 (pad 50016)
    int* bsum    = offs + 50016;                                 // 64
    int* csr_src = bsum + 64;                                    // E

    // ---- prep + CSR build (8 dispatches total, was 12)
    prep_kernel<<<48, 256, 0, stream>>>(W0, W1, wt0, wt1, counts);
    hist_kernel<<<(N_EDGES + 255) / 256, 256, 0, stream>>>(dst, counts, N_EDGES);
    scan_one<<<1, 1024, 0, stream>>>(counts, offs, N_NODES);
    scatter_kernel<<<(N_EDGES + 255) / 256, 256, 0, stream>>>(src, dst, offs, cursor, csr_src, N_EDGES);

    const int ggrid = (N_NODES + 127) / 128;   // 391

    // ---- layer 1 (A from fp32 x; h1 fp16 written into d_out)
    mfma_gemm<1><<<ggrid, 512, 0, stream>>>(nullptr, x, wt0, al0, ar0, feat16, el, er);
    agg_fused<<<N_NODES / 4, 256, 0, stream>>>(feat16, el, er, b0, offs, csr_src,
                                               out, h1, 0);

    // ---- layer 2 (reads h1 fp16; final head-major fp32 write to d_out)
    mfma_gemm<0><<<ggrid, 512, 0, stream>>>(h1, nullptr, wt1, al1, ar1, feat16, el, er);
    agg_fused<<<N_NODES / 4, 256, 0, stream>>>(feat16, el, er, b1, offs, csr_src,
                                               out, h1, 1);
}

// Round 9
// 374.964 us; speedup vs baseline: 1.0577x; 1.0577x over previous
//
#include <hip/hip_runtime.h>
#include <math.h>

#define N_NODES 50000
#define N_EDGES 800000
#define HEADS 4
#define HID 64
#define FDIM 256      // HEADS*HID == F_IN == 256 for both layers
#define LDA 40        // padded LDS k-stride (halves): 80B row stride
#define SCAN_CHUNK 1024
#define SCAN_NB ((N_NODES + SCAN_CHUNK - 1) / SCAN_CHUNK)   // 49

typedef __attribute__((ext_vector_type(8))) _Float16 half8;
typedef __attribute__((ext_vector_type(4))) _Float16 half4;
typedef __attribute__((ext_vector_type(4))) float f32x4;

// ---------------------------------------------------------------- CSR build
// R6 lesson: no grid.sync fusion (~100us/sync). R8 lesson: dispatch-count
// reduction per se buys nothing (graph-captured launches are cheap) — only
// fuse work that OVERLAPS (e.g. hist inside gemm-1, see below).

__global__ __launch_bounds__(256) void scan_local(const int* __restrict__ counts,
                                                  int* __restrict__ offs,
                                                  int* __restrict__ bsum, int n) {
    __shared__ int part[256];
    const int b = blockIdx.x, t = threadIdx.x;
    const int base = b * SCAN_CHUNK + t * 4;
    int v[4];
#pragma unroll
    for (int j = 0; j < 4; j++) {
        int idx = base + j;
        v[j] = (idx < n) ? counts[idx] : 0;
    }
    int s0 = v[0], s1 = s0 + v[1], s2 = s1 + v[2], s3 = s2 + v[3];
    part[t] = s3;
    __syncthreads();
    for (int off = 1; off < 256; off <<= 1) {
        int x = (t >= off) ? part[t - off] : 0;
        __syncthreads();
        part[t] += x;
        __syncthreads();
    }
    int prefix = (t > 0) ? part[t - 1] : 0;
    int e[4] = {prefix, prefix + s0, prefix + s1, prefix + s2};
#pragma unroll
    for (int j = 0; j < 4; j++) {
        int idx = base + j;
        if (idx < n) offs[idx] = e[j];
    }
    if (t == 255) bsum[b] = part[255];
}

__global__ __launch_bounds__(64) void scan_bsum(int* __restrict__ bsum,
                                                int* __restrict__ offs, int nb, int n) {
    int lane = threadIdx.x;
    int own = (lane < nb) ? bsum[lane] : 0;
    int v = own;
    for (int off = 1; off < 64; off <<= 1) {
        int x = __shfl_up(v, off);
        if (lane >= off) v += x;
    }
    if (lane < nb) bsum[lane] = v - own;   // exclusive prefix
    if (lane == nb - 1) offs[n] = v;       // grand total
}

__global__ __launch_bounds__(256) void scan_add(int* __restrict__ offs,
                                                const int* __restrict__ bsum, int n) {
    const int b = blockIdx.x;
    const int p = bsum[b];
    const int base = b * SCAN_CHUNK + threadIdx.x * 4;
#pragma unroll
    for (int j = 0; j < 4; j++) {
        int idx = base + j;
        if (idx < n) offs[idx] += p;
    }
}

__global__ __launch_bounds__(256) void scatter_kernel(const int* __restrict__ src,
                                                      const int* __restrict__ dst,
                                                      const int* __restrict__ offs,
                                                      int* __restrict__ cursor,
                                                      int* __restrict__ csr_src, int E) {
    int i = blockIdx.x * blockDim.x + threadIdx.x;
    if (i < E) {
        int d = dst[i];
        int p = offs[d] + atomicAdd(&cursor[d], 1);
        csr_src[p] = src[i];
    }
}

// -------------------------------------------- prep: W transpose-cast

__global__ __launch_bounds__(256) void wcast_kernel(const float* __restrict__ W0,
                                                    const float* __restrict__ W1,
                                                    _Float16* __restrict__ wt0,
                                                    _Float16* __restrict__ wt1) {
    const float* W = blockIdx.y ? W1 : W0;
    _Float16* wt = blockIdx.y ? wt1 : wt0;
    int n = blockIdx.x * 16 + (threadIdx.x >> 4);
    int k0 = (threadIdx.x & 15) * 16;
    for (int j = 0; j < 16; j++)
        wt[n * FDIM + k0 + j] = (_Float16)W[(k0 + j) * FDIM + n];
}

// -------------------------------------------- fp16 MFMA GEMM + fused el/er
// v6 = v5 + DO_HIST: gemm-1 runs the CSR histogram in its prologue.
// Non-returning global atomicAdd issues fire-and-forget (no waitcnt dep
// until kernel end), so the 800K atomics drain in the shadow of the GEMM's
// staging+MFMA phases — hides the ~15-20us hist dispatch entirely.
// v5: operand-SWAPPED mfma — acc[mt][nt] = mfma(bf[nt], af[mt], ...) puts
// the C fragment in transposed lane order: l16 = m-row, quad*4+r = 4
// consecutive n-cols -> 8B vector stores; el/er via per-lane float4 FMA +
// 2 shuffles. BN=256 (whole N per block), 512 threads / 8 waves, 64x64 per
// wave. A32: stage A directly from fp32 (layer 1, no cast pass).
template <int A32, int DO_HIST>
__global__ __launch_bounds__(512) void mfma_gemm(const _Float16* __restrict__ A16,
                                                 const float* __restrict__ Af,
                                                 const _Float16* __restrict__ Bt,
                                                 const float* __restrict__ al,
                                                 const float* __restrict__ ar,
                                                 _Float16* __restrict__ feat16,
                                                 float* __restrict__ el,
                                                 float* __restrict__ er,
                                                 const int* __restrict__ dst,
                                                 int* __restrict__ counts) {
    __shared__ _Float16 ash[128][LDA];
    __shared__ _Float16 bsh[256][LDA];

    const int t = threadIdx.x;
    const int m0 = blockIdx.x * 128;
    const int wave = t >> 6, lane = t & 63;
    const int quad = lane >> 4, l16 = lane & 15;
    const int wr = (wave >> 2) * 64;
    const int wc = (wave & 3) * 64;

    if (DO_HIST) {
        // grid-strided histogram; atomics complete asynchronously under GEMM
        const int NT = gridDim.x * 512;
        for (int i = blockIdx.x * 512 + t; i < N_EDGES; i += NT)
            atomicAdd(&counts[dst[i]], 1);
    }

    const f32x4 zero = {0.f, 0.f, 0.f, 0.f};
    f32x4 acc[4][4];
#pragma unroll
    for (int i = 0; i < 4; i++)
#pragma unroll
        for (int j = 0; j < 4; j++) acc[i][j] = zero;

    for (int kk = 0; kk < FDIM; kk += 32) {
        // ---- stage A: 128 rows x 32 halves = 512 x 8-half chunks, 1/thread
        {
            int row = t >> 2;
            int kb = (t & 3) * 8;
            int gr = m0 + row; if (gr >= N_NODES) gr = N_NODES - 1;
            if (A32) {
                const float* p = &Af[(size_t)gr * FDIM + kk + kb];
                float4 f0 = *(const float4*)p;
                float4 f1 = *(const float4*)(p + 4);
                half8 hv = {(_Float16)f0.x, (_Float16)f0.y, (_Float16)f0.z, (_Float16)f0.w,
                            (_Float16)f1.x, (_Float16)f1.y, (_Float16)f1.z, (_Float16)f1.w};
                *(half8*)&ash[row][kb] = hv;
            } else {
                *(half8*)&ash[row][kb] = *(const half8*)&A16[(size_t)gr * FDIM + kk + kb];
            }
        }
        // ---- stage B: 256 rows x 32 halves = 1024 chunks, 2/thread
#pragma unroll
        for (int ii = 0; ii < 2; ii++) {
            int idx = t + ii * 512;
            int row = idx >> 2;
            int kb = (idx & 3) * 8;
            *(half8*)&bsh[row][kb] = *(const half8*)&Bt[(size_t)row * FDIM + kk + kb];
        }
        __syncthreads();

        half8 af[4], bf[4];
#pragma unroll
        for (int i = 0; i < 4; i++) {
            af[i] = *(half8*)&ash[wr + i * 16 + l16][quad * 8];
            bf[i] = *(half8*)&bsh[wc + i * 16 + l16][quad * 8];
        }
        // swapped operands: C fragment transposed (l16 = m-row, quad*4+r = n-col)
#pragma unroll
        for (int mt = 0; mt < 4; mt++)
#pragma unroll
            for (int nt = 0; nt < 4; nt++)
                acc[mt][nt] = __builtin_amdgcn_mfma_f32_16x16x32_f16(bf[nt], af[mt], acc[mt][nt], 0, 0, 0);
        __syncthreads();
    }

    // ---- epilogue: vector feat16 store + fused el/er (this wave's head = h)
    const int h = wc >> 6;
    float4 alv[4], arv[4];
#pragma unroll
    for (int nt = 0; nt < 4; nt++) {
        alv[nt] = *(const float4*)&al[wc + nt * 16 + quad * 4];
        arv[nt] = *(const float4*)&ar[wc + nt * 16 + quad * 4];
    }
#pragma unroll
    for (int mt = 0; mt < 4; mt++) {
        const int m = m0 + wr + mt * 16 + l16;
        const bool ok = (m < N_NODES);
        float pl = 0.f, pr = 0.f;
#pragma unroll
        for (int nt = 0; nt < 4; nt++) {
            f32x4 v = acc[mt][nt];
            if (ok) {
                half4 hv = {(_Float16)v[0], (_Float16)v[1], (_Float16)v[2], (_Float16)v[3]};
                *(half4*)&feat16[(size_t)m * FDIM + wc + nt * 16 + quad * 4] = hv;
            }
            pl += v[0] * alv[nt].x + v[1] * alv[nt].y + v[2] * alv[nt].z + v[3] * alv[nt].w;
            pr += v[0] * arv[nt].x + v[1] * arv[nt].y + v[2] * arv[nt].z + v[3] * arv[nt].w;
        }
        // reduce over the 4 quads (lanes l16, l16+16, l16+32, l16+48)
        pl += __shfl_xor(pl, 16);
        pl += __shfl_xor(pl, 32);
        pr += __shfl_xor(pr, 16);
        pr += __shfl_xor(pr, 32);
        if (quad == 0 && ok) {
            el[m * 4 + h] = pl;
            er[m * 4 + h] = pr;
        }
    }
}

// ------------------------------------------- fused softmax + aggregate
// Wave per node, NO LDS / NO barriers. Lane owns features f=lane*4..+3
// (head = lane>>4).
//
// v2 (best measured; traffic-bound at ~3.9 TB/s beyond-L2, invariant to
// scheduling): cooperative weights. Edges walked in 16-chunks; W-phase:
// lane (lane&15)==j computes edge c+j's weight for its OWN head;
// MAC-phase broadcasts (s,w) via __shfl, 4-wide. Denominator accumulated
// per-lane, reduced once at the end. Single-pass softmax.
// mode 0: write h1 as fp16 (layer-2 GEMM input, lives in d_out)
// mode 1: final fp32 head-major write
__global__ __launch_bounds__(256) void agg_fused(const _Float16* __restrict__ feat16,
                                                 const float* __restrict__ el,
                                                 const float* __restrict__ er,
                                                 const float* __restrict__ bias,
                                                 const int* __restrict__ offs,
                                                 const int* __restrict__ csr_src,
                                                 float* __restrict__ out,
                                                 _Float16* __restrict__ h1,
                                                 int mode) {
    const int wave = threadIdx.x >> 6;
    const int lane = threadIdx.x & 63;
    const int n = blockIdx.x * 4 + wave;
    const int head = lane >> 4;
    const int f = lane * 4;           // == head*64 + (lane&15)*4
    const int base16 = lane & 48;     // first lane of this head's 16-group
    const int j16 = lane & 15;
    const int beg = offs[n];
    const int end = offs[n + 1];
    const float er_h = er[n * 4 + head];

    float4 acc = make_float4(0.f, 0.f, 0.f, 0.f);
    float ss = 0.f;

    for (int c = beg; c < end; c += 16) {
        // ---- W-phase: this lane owns edge c + j16 (for its own head)
        int e = c + j16;
        int s_own = 0;
        float w_own = 0.f;
        if (e < end) {
            s_own = csr_src[e];
            float lg = el[s_own * 4 + head] + er_h;
            lg = (lg > 0.f) ? lg : 0.2f * lg;
            w_own = __expf(lg);
        }
        ss += w_own;

        int rem = end - c;
        if (rem > 16) rem = 16;

        // ---- MAC-phase: walk the chunk's edges, s/w via shuffle broadcast
        int j = 0;
        for (; j + 3 < rem; j += 4) {
            int s0 = __shfl(s_own, base16 + j);
            int s1 = __shfl(s_own, base16 + j + 1);
            int s2 = __shfl(s_own, base16 + j + 2);
            int s3 = __shfl(s_own, base16 + j + 3);
            float w0 = __shfl(w_own, base16 + j);
            float w1 = __shfl(w_own, base16 + j + 1);
            float w2 = __shfl(w_own, base16 + j + 2);
            float w3 = __shfl(w_own, base16 + j + 3);
            half4 v0 = *(const half4*)&feat16[(size_t)s0 * FDIM + f];
            half4 v1 = *(const half4*)&feat16[(size_t)s1 * FDIM + f];
            half4 v2 = *(const half4*)&feat16[(size_t)s2 * FDIM + f];
            half4 v3 = *(const half4*)&feat16[(size_t)s3 * FDIM + f];
            acc.x += w0 * (float)v0[0] + w1 * (float)v1[0];
            acc.y += w0 * (float)v0[1] + w1 * (float)v1[1];
            acc.z += w0 * (float)v0[2] + w1 * (float)v1[2];
            acc.w += w0 * (float)v0[3] + w1 * (float)v1[3];
            acc.x += w2 * (float)v2[0] + w3 * (float)v3[0];
            acc.y += w2 * (float)v2[1] + w3 * (float)v3[1];
            acc.z += w2 * (float)v2[2] + w3 * (float)v3[2];
            acc.w += w2 * (float)v2[3] + w3 * (float)v3[3];
        }
        for (; j < rem; j++) {
            int s0 = __shfl(s_own, base16 + j);
            float w0 = __shfl(w_own, base16 + j);
            half4 v0 = *(const half4*)&feat16[(size_t)s0 * FDIM + f];
            acc.x += w0 * (float)v0[0];
            acc.y += w0 * (float)v0[1];
            acc.z += w0 * (float)v0[2];
            acc.w += w0 * (float)v0[3];
        }
    }

    // ---- reduce softmax denominator across the 16-lane head group
    ss += __shfl_xor(ss, 1, 16);
    ss += __shfl_xor(ss, 2, 16);
    ss += __shfl_xor(ss, 4, 16);
    ss += __shfl_xor(ss, 8, 16);

    float S = fmaxf(ss, 1e-9f);
    float inv = 1.f / S;
    float4 bv = *(const float4*)&bias[f];
    float r0 = acc.x * inv + bv.x;
    float r1 = acc.y * inv + bv.y;
    float r2 = acc.z * inv + bv.z;
    float r3 = acc.w * inv + bv.w;
    r0 = (r0 > 0.f) ? r0 : expm1f(r0);
    r1 = (r1 > 0.f) ? r1 : expm1f(r1);
    r2 = (r2 > 0.f) ? r2 : expm1f(r2);
    r3 = (r3 > 0.f) ? r3 : expm1f(r3);

    if (mode) {
        const int d = (lane & 15) * 4;
        float4 rv = make_float4(r0, r1, r2, r3);
        *(float4*)&out[(size_t)head * N_NODES * HID + (size_t)n * HID + d] = rv;
    } else {
        half4 hv = {(_Float16)r0, (_Float16)r1, (_Float16)r2, (_Float16)r3};
        *(half4*)&h1[(size_t)n * FDIM + f] = hv;
    }
}

// ---------------------------------------------------------------- launch

extern "C" void kernel_launch(void* const* d_in, const int* in_sizes, int n_in,
                              void* d_out, int out_size, void* d_ws, size_t ws_size,
                              hipStream_t stream) {
    const float* x   = (const float*)d_in[0];
    const int*   src = (const int*)d_in[1];
    const int*   dst = (const int*)d_in[2];
    const float* W0  = (const float*)d_in[3];
    const float* al0 = (const float*)d_in[4];
    const float* ar0 = (const float*)d_in[5];
    const float* b0  = (const float*)d_in[6];
    const float* W1  = (const float*)d_in[7];
    const float* al1 = (const float*)d_in[8];
    const float* ar1 = (const float*)d_in[9];
    const float* b1  = (const float*)d_in[10];
    float* out = (float*)d_out;

    // h1 (layer-1 hidden, fp16) lives in the first 25.6 MB of d_out.
    // Timeline: gemm-1 reads x fp32 directly -> agg(mode0) writes h1 ->
    // gemm-2 reads h1 -> agg(mode1) overwrites all of d_out with the final
    // output. All sequential on stream.
    _Float16* h1 = (_Float16*)d_out;

    // workspace layout
    _Float16* feat16 = (_Float16*)d_ws;                          // N*256 fp16
    _Float16* wt0 = feat16 + (size_t)N_NODES * FDIM;             // 256*256
    _Float16* wt1 = wt0 + FDIM * FDIM;                           // 256*256
    float* el    = (float*)(wt1 + FDIM * FDIM);                  // N*4
    float* er    = el + N_NODES * HEADS;                         // N*4
    int* counts  = (int*)(er + N_NODES * HEADS);                 // N
    int* cursor  = counts + N_NODES;                             // N
    int* offs    = cursor + N_NODES;                             // N+1 (pad 50016)
    int* bsum    = offs + 50016;                                 // 64
    int* csr_src = bsum + 64;                                    // E

    const int ggrid = (N_NODES + 127) / 128;   // 391

    // ---- prep; hist is fused into gemm-1 (overlapped, not serialized)
    hipMemsetAsync(counts, 0, 2 * N_NODES * sizeof(int), stream);  // counts + cursor
    wcast_kernel<<<dim3(16, 2), 256, 0, stream>>>(W0, W1, wt0, wt1);

    // ---- layer-1 GEMM + histogram (A from fp32 x; hist atomics overlap GEMM)
    mfma_gemm<1, 1><<<ggrid, 512, 0, stream>>>(nullptr, x, wt0, al0, ar0,
                                               feat16, el, er, dst, counts);

    // ---- CSR scan + scatter (hist results ready after gemm-1 completes)
    scan_local<<<SCAN_NB, 256, 0, stream>>>(counts, offs, bsum, N_NODES);
    scan_bsum<<<1, 64, 0, stream>>>(bsum, offs, SCAN_NB, N_NODES);
    scan_add<<<SCAN_NB, 256, 0, stream>>>(offs, bsum, N_NODES);
    scatter_kernel<<<(N_EDGES + 255) / 256, 256, 0, stream>>>(src, dst, offs, cursor, csr_src, N_EDGES);

    // ---- layer 1 aggregate (h1 fp16 written into d_out)
    agg_fused<<<N_NODES / 4, 256, 0, stream>>>(feat16, el, er, b0, offs, csr_src,
                                               out, h1, 0);

    // ---- layer 2 (reads h1 fp16; final head-major fp32 write to d_out)
    mfma_gemm<0, 0><<<ggrid, 512, 0, stream>>>(h1, nullptr, wt1, al1, ar1,
                                               feat16, el, er, nullptr, nullptr);
    agg_fused<<<N_NODES / 4, 256, 0, stream>>>(feat16, el, er, b1, offs, csr_src,
                                               out, h1, 1);
}

// Round 10
// 367.368 us; speedup vs baseline: 1.0795x; 1.0207x over previous
//
#include <hip/hip_runtime.h>
#include <math.h>

#define N_NODES 50000
#define N_EDGES 800000
#define HEADS 4
#define HID 64
#define FDIM 256      // HEADS*HID == F_IN == 256 for both layers
#define SCAN_CHUNK 1024
#define SCAN_NB ((N_NODES + SCAN_CHUNK - 1) / SCAN_CHUNK)   // 49

typedef __attribute__((ext_vector_type(8))) _Float16 half8;
typedef __attribute__((ext_vector_type(4))) _Float16 half4;
typedef __attribute__((ext_vector_type(4))) float f32x4;

// ---------------------------------------------------------------- CSR build
// R6 lesson: no grid.sync fusion (~100us/sync). R8 lesson: dispatch-count
// reduction per se buys nothing — only fuse work that OVERLAPS (hist is
// fused into gemm-1's prologue below).

__global__ __launch_bounds__(256) void scan_local(const int* __restrict__ counts,
                                                  int* __restrict__ offs,
                                                  int* __restrict__ bsum, int n) {
    __shared__ int part[256];
    const int b = blockIdx.x, t = threadIdx.x;
    const int base = b * SCAN_CHUNK + t * 4;
    int v[4];
#pragma unroll
    for (int j = 0; j < 4; j++) {
        int idx = base + j;
        v[j] = (idx < n) ? counts[idx] : 0;
    }
    int s0 = v[0], s1 = s0 + v[1], s2 = s1 + v[2], s3 = s2 + v[3];
    part[t] = s3;
    __syncthreads();
    for (int off = 1; off < 256; off <<= 1) {
        int x = (t >= off) ? part[t - off] : 0;
        __syncthreads();
        part[t] += x;
        __syncthreads();
    }
    int prefix = (t > 0) ? part[t - 1] : 0;
    int e[4] = {prefix, prefix + s0, prefix + s1, prefix + s2};
#pragma unroll
    for (int j = 0; j < 4; j++) {
        int idx = base + j;
        if (idx < n) offs[idx] = e[j];
    }
    if (t == 255) bsum[b] = part[255];
}

__global__ __launch_bounds__(64) void scan_bsum(int* __restrict__ bsum,
                                                int* __restrict__ offs, int nb, int n) {
    int lane = threadIdx.x;
    int own = (lane < nb) ? bsum[lane] : 0;
    int v = own;
    for (int off = 1; off < 64; off <<= 1) {
        int x = __shfl_up(v, off);
        if (lane >= off) v += x;
    }
    if (lane < nb) bsum[lane] = v - own;   // exclusive prefix
    if (lane == nb - 1) offs[n] = v;       // grand total
}

__global__ __launch_bounds__(256) void scan_add(int* __restrict__ offs,
                                                const int* __restrict__ bsum, int n) {
    const int b = blockIdx.x;
    const int p = bsum[b];
    const int base = b * SCAN_CHUNK + threadIdx.x * 4;
#pragma unroll
    for (int j = 0; j < 4; j++) {
        int idx = base + j;
        if (idx < n) offs[idx] += p;
    }
}

__global__ __launch_bounds__(256) void scatter_kernel(const int* __restrict__ src,
                                                      const int* __restrict__ dst,
                                                      const int* __restrict__ offs,
                                                      int* __restrict__ cursor,
                                                      int* __restrict__ csr_src, int E) {
    int i = blockIdx.x * blockDim.x + threadIdx.x;
    if (i < E) {
        int d = dst[i];
        int p = offs[d] + atomicAdd(&cursor[d], 1);
        csr_src[p] = src[i];
    }
}

// -------------------------------------------- prep: W transpose-cast

__global__ __launch_bounds__(256) void wcast_kernel(const float* __restrict__ W0,
                                                    const float* __restrict__ W1,
                                                    _Float16* __restrict__ wt0,
                                                    _Float16* __restrict__ wt1) {
    const float* W = blockIdx.y ? W1 : W0;
    _Float16* wt = blockIdx.y ? wt1 : wt0;
    int n = blockIdx.x * 16 + (threadIdx.x >> 4);
    int k0 = (threadIdx.x & 15) * 16;
    for (int j = 0; j < 16; j++)
        wt[n * FDIM + k0 + j] = (_Float16)W[(k0 + j) * FDIM + n];
}

// -------------------------------------------- fp16 MFMA GEMM + fused el/er
// v7: GEMM was latency/occupancy-bound (R9 counters: MfmaUtil 3.5%,
// VALUBusy 3.6%, Occupancy 16%, 1.4M LDS bank conflicts — grid of 391
// blocks = 1.5/CU left nothing to hide staging latency).
//  - BM=64 -> 782 blocks (3/CU), 512 threads / 8 waves (2 rowbands x 4
//    colbands, 32x64 per wave, acc[2][4]); LDS 20KB -> 4 blocks/CU possible.
//  - XOR-swizzled LDS (64B row stride; 16B slot ^ (row&3) ^ ((row>>2)&3)):
//    uniform 2-way bank pattern (free) vs old ~8-way at 80B stride.
//  - keeps: swapped-operand mfma epilogue (l16 = m-row, quad*4+r = n-col,
//    8B vector stores, el/er via float4 FMA + 2 shuffles); fp32-A staging
//    (layer 1, template A32); hist fused in prologue (DO_HIST) — 800K
//    fire-and-forget atomics drain under the GEMM.
template <int A32, int DO_HIST>
__global__ __launch_bounds__(512) void mfma_gemm(const _Float16* __restrict__ A16,
                                                 const float* __restrict__ Af,
                                                 const _Float16* __restrict__ Bt,
                                                 const float* __restrict__ al,
                                                 const float* __restrict__ ar,
                                                 _Float16* __restrict__ feat16,
                                                 float* __restrict__ el,
                                                 float* __restrict__ er,
                                                 const int* __restrict__ dst,
                                                 int* __restrict__ counts) {
    __shared__ _Float16 ash[64 * 32];    // 4 KB,  64 rows x 32 halves (swizzled)
    __shared__ _Float16 bsh[256 * 32];   // 16 KB, 256 rows x 32 halves (swizzled)

    const int t = threadIdx.x;
    const int m0 = blockIdx.x * 64;
    const int wave = t >> 6, lane = t & 63;
    const int quad = lane >> 4, l16 = lane & 15;
    const int wr = (wave >> 2) * 32;     // rowband: 0 or 32
    const int wc = (wave & 3) * 64;      // colband: 0/64/128/192 (== head*64)

    if (DO_HIST) {
        // grid-strided histogram; atomics complete asynchronously under GEMM
        for (int i = blockIdx.x * 512 + t; i < N_EDGES; i += gridDim.x * 512)
            atomicAdd(&counts[dst[i]], 1);
    }

    const f32x4 zero = {0.f, 0.f, 0.f, 0.f};
    f32x4 acc[2][4];
#pragma unroll
    for (int i = 0; i < 2; i++)
#pragma unroll
        for (int j = 0; j < 4; j++) acc[i][j] = zero;

    // reader slot (halves): same for all fragment rows since wr/wc/nt*16 are
    // multiples of 16 -> row&3 == l16&3, (row>>2)&3 == l16>>2
    const int rslot = ((quad ^ (l16 & 3) ^ (l16 >> 2)) * 8);

    for (int kk = 0; kk < FDIM; kk += 32) {
        // ---- stage A: 64 rows x 32 halves; threads 0..255, 8 halves each
        if (t < 256) {
            int row = t >> 2, slotL = t & 3;
            int ps = ((slotL ^ (row & 3) ^ ((row >> 2) & 3)) * 8);
            int gr = m0 + row; if (gr >= N_NODES) gr = N_NODES - 1;
            if (A32) {
                const float* p = &Af[(size_t)gr * FDIM + kk + slotL * 8];
                float4 f0 = *(const float4*)p;
                float4 f1 = *(const float4*)(p + 4);
                half8 hv = {(_Float16)f0.x, (_Float16)f0.y, (_Float16)f0.z, (_Float16)f0.w,
                            (_Float16)f1.x, (_Float16)f1.y, (_Float16)f1.z, (_Float16)f1.w};
                *(half8*)&ash[row * 32 + ps] = hv;
            } else {
                *(half8*)&ash[row * 32 + ps] =
                    *(const half8*)&A16[(size_t)gr * FDIM + kk + slotL * 8];
            }
        }
        // ---- stage B: 256 rows x 32 halves = 1024 chunks, 2/thread
#pragma unroll
        for (int ii = 0; ii < 2; ii++) {
            int idx = t + ii * 512;
            int row = idx >> 2, slotL = idx & 3;
            int ps = ((slotL ^ (row & 3) ^ ((row >> 2) & 3)) * 8);
            *(half8*)&bsh[row * 32 + ps] =
                *(const half8*)&Bt[(size_t)row * FDIM + kk + slotL * 8];
        }
        __syncthreads();

        half8 af[2], bf[4];
#pragma unroll
        for (int i = 0; i < 2; i++)
            af[i] = *(half8*)&ash[(wr + i * 16 + l16) * 32 + rslot];
#pragma unroll
        for (int i = 0; i < 4; i++)
            bf[i] = *(half8*)&bsh[(wc + i * 16 + l16) * 32 + rslot];

        // swapped operands: C fragment transposed (l16 = m-row, quad*4+r = n-col)
#pragma unroll
        for (int mt = 0; mt < 2; mt++)
#pragma unroll
            for (int nt = 0; nt < 4; nt++)
                acc[mt][nt] = __builtin_amdgcn_mfma_f32_16x16x32_f16(bf[nt], af[mt], acc[mt][nt], 0, 0, 0);
        __syncthreads();
    }

    // ---- epilogue: vector feat16 store + fused el/er (this wave's head = h)
    const int h = wc >> 6;
    float4 alv[4], arv[4];
#pragma unroll
    for (int nt = 0; nt < 4; nt++) {
        alv[nt] = *(const float4*)&al[wc + nt * 16 + quad * 4];
        arv[nt] = *(const float4*)&ar[wc + nt * 16 + quad * 4];
    }
#pragma unroll
    for (int mt = 0; mt < 2; mt++) {
        const int m = m0 + wr + mt * 16 + l16;
        const bool ok = (m < N_NODES);
        float pl = 0.f, pr = 0.f;
#pragma unroll
        for (int nt = 0; nt < 4; nt++) {
            f32x4 v = acc[mt][nt];
            if (ok) {
                half4 hv = {(_Float16)v[0], (_Float16)v[1], (_Float16)v[2], (_Float16)v[3]};
                *(half4*)&feat16[(size_t)m * FDIM + wc + nt * 16 + quad * 4] = hv;
            }
            pl += v[0] * alv[nt].x + v[1] * alv[nt].y + v[2] * alv[nt].z + v[3] * alv[nt].w;
            pr += v[0] * arv[nt].x + v[1] * arv[nt].y + v[2] * arv[nt].z + v[3] * arv[nt].w;
        }
        // reduce over the 4 quads (lanes l16, l16+16, l16+32, l16+48)
        pl += __shfl_xor(pl, 16);
        pl += __shfl_xor(pl, 32);
        pr += __shfl_xor(pr, 16);
        pr += __shfl_xor(pr, 32);
        if (quad == 0 && ok) {
            el[m * 4 + h] = pl;
            er[m * 4 + h] = pr;
        }
    }
}

// ------------------------------------------- fused softmax + aggregate
// Wave per node, NO LDS / NO barriers. Lane owns features f=lane*4..+3
// (head = lane>>4).
//
// v2 (best measured; traffic-bound at ~3.9 TB/s beyond-L2, invariant to
// scheduling): cooperative weights. Edges walked in 16-chunks; W-phase:
// lane (lane&15)==j computes edge c+j's weight for its OWN head;
// MAC-phase broadcasts (s,w) via __shfl, 4-wide. Denominator accumulated
// per-lane, reduced once at the end. Single-pass softmax.
// mode 0: write h1 as fp16 (layer-2 GEMM input, lives in d_out)
// mode 1: final fp32 head-major write
__global__ __launch_bounds__(256) void agg_fused(const _Float16* __restrict__ feat16,
                                                 const float* __restrict__ el,
                                                 const float* __restrict__ er,
                                                 const float* __restrict__ bias,
                                                 const int* __restrict__ offs,
                                                 const int* __restrict__ csr_src,
                                                 float* __restrict__ out,
                                                 _Float16* __restrict__ h1,
                                                 int mode) {
    const int wave = threadIdx.x >> 6;
    const int lane = threadIdx.x & 63;
    const int n = blockIdx.x * 4 + wave;
    const int head = lane >> 4;
    const int f = lane * 4;           // == head*64 + (lane&15)*4
    const int base16 = lane & 48;     // first lane of this head's 16-group
    const int j16 = lane & 15;
    const int beg = offs[n];
    const int end = offs[n + 1];
    const float er_h = er[n * 4 + head];

    float4 acc = make_float4(0.f, 0.f, 0.f, 0.f);
    float ss = 0.f;

    for (int c = beg; c < end; c += 16) {
        // ---- W-phase: this lane owns edge c + j16 (for its own head)
        int e = c + j16;
        int s_own = 0;
        float w_own = 0.f;
        if (e < end) {
            s_own = csr_src[e];
            float lg = el[s_own * 4 + head] + er_h;
            lg = (lg > 0.f) ? lg : 0.2f * lg;
            w_own = __expf(lg);
        }
        ss += w_own;

        int rem = end - c;
        if (rem > 16) rem = 16;

        // ---- MAC-phase: walk the chunk's edges, s/w via shuffle broadcast
        int j = 0;
        for (; j + 3 < rem; j += 4) {
            int s0 = __shfl(s_own, base16 + j);
            int s1 = __shfl(s_own, base16 + j + 1);
            int s2 = __shfl(s_own, base16 + j + 2);
            int s3 = __shfl(s_own, base16 + j + 3);
            float w0 = __shfl(w_own, base16 + j);
            float w1 = __shfl(w_own, base16 + j + 1);
            float w2 = __shfl(w_own, base16 + j + 2);
            float w3 = __shfl(w_own, base16 + j + 3);
            half4 v0 = *(const half4*)&feat16[(size_t)s0 * FDIM + f];
            half4 v1 = *(const half4*)&feat16[(size_t)s1 * FDIM + f];
            half4 v2 = *(const half4*)&feat16[(size_t)s2 * FDIM + f];
            half4 v3 = *(const half4*)&feat16[(size_t)s3 * FDIM + f];
            acc.x += w0 * (float)v0[0] + w1 * (float)v1[0];
            acc.y += w0 * (float)v0[1] + w1 * (float)v1[1];
            acc.z += w0 * (float)v0[2] + w1 * (float)v1[2];
            acc.w += w0 * (float)v0[3] + w1 * (float)v1[3];
            acc.x += w2 * (float)v2[0] + w3 * (float)v3[0];
            acc.y += w2 * (float)v2[1] + w3 * (float)v3[1];
            acc.z += w2 * (float)v2[2] + w3 * (float)v3[2];
            acc.w += w2 * (float)v2[3] + w3 * (float)v3[3];
        }
        for (; j < rem; j++) {
            int s0 = __shfl(s_own, base16 + j);
            float w0 = __shfl(w_own, base16 + j);
            half4 v0 = *(const half4*)&feat16[(size_t)s0 * FDIM + f];
            acc.x += w0 * (float)v0[0];
            acc.y += w0 * (float)v0[1];
            acc.z += w0 * (float)v0[2];
            acc.w += w0 * (float)v0[3];
        }
    }

    // ---- reduce softmax denominator across the 16-lane head group
    ss += __shfl_xor(ss, 1, 16);
    ss += __shfl_xor(ss, 2, 16);
    ss += __shfl_xor(ss, 4, 16);
    ss += __shfl_xor(ss, 8, 16);

    float S = fmaxf(ss, 1e-9f);
    float inv = 1.f / S;
    float4 bv = *(const float4*)&bias[f];
    float r0 = acc.x * inv + bv.x;
    float r1 = acc.y * inv + bv.y;
    float r2 = acc.z * inv + bv.z;
    float r3 = acc.w * inv + bv.w;
    r0 = (r0 > 0.f) ? r0 : expm1f(r0);
    r1 = (r1 > 0.f) ? r1 : expm1f(r1);
    r2 = (r2 > 0.f) ? r2 : expm1f(r2);
    r3 = (r3 > 0.f) ? r3 : expm1f(r3);

    if (mode) {
        const int d = (lane & 15) * 4;
        float4 rv = make_float4(r0, r1, r2, r3);
        *(float4*)&out[(size_t)head * N_NODES * HID + (size_t)n * HID + d] = rv;
    } else {
        half4 hv = {(_Float16)r0, (_Float16)r1, (_Float16)r2, (_Float16)r3};
        *(half4*)&h1[(size_t)n * FDIM + f] = hv;
    }
}

// ---------------------------------------------------------------- launch

extern "C" void kernel_launch(void* const* d_in, const int* in_sizes, int n_in,
                              void* d_out, int out_size, void* d_ws, size_t ws_size,
                              hipStream_t stream) {
    const float* x   = (const float*)d_in[0];
    const int*   src = (const int*)d_in[1];
    const int*   dst = (const int*)d_in[2];
    const float* W0  = (const float*)d_in[3];
    const float* al0 = (const float*)d_in[4];
    const float* ar0 = (const float*)d_in[5];
    const float* b0  = (const float*)d_in[6];
    const float* W1  = (const float*)d_in[7];
    const float* al1 = (const float*)d_in[8];
    const float* ar1 = (const float*)d_in[9];
    const float* b1  = (const float*)d_in[10];
    float* out = (float*)d_out;

    // h1 (layer-1 hidden, fp16) lives in the first 25.6 MB of d_out.
    // Timeline: gemm-1 reads x fp32 directly -> agg(mode0) writes h1 ->
    // gemm-2 reads h1 -> agg(mode1) overwrites all of d_out with the final
    // output. All sequential on stream.
    _Float16* h1 = (_Float16*)d_out;

    // workspace layout
    _Float16* feat16 = (_Float16*)d_ws;                          // N*256 fp16
    _Float16* wt0 = feat16 + (size_t)N_NODES * FDIM;             // 256*256
    _Float16* wt1 = wt0 + FDIM * FDIM;                           // 256*256
    float* el    = (float*)(wt1 + FDIM * FDIM);                  // N*4
    float* er    = el + N_NODES * HEADS;                         // N*4
    int* counts  = (int*)(er + N_NODES * HEADS);                 // N
    int* cursor  = counts + N_NODES;                             // N
    int* offs    = cursor + N_NODES;                             // N+1 (pad 50016)
    int* bsum    = offs + 50016;                                 // 64
    int* csr_src = bsum + 64;                                    // E

    const int ggrid = (N_NODES + 63) / 64;   // 782

    // ---- prep; hist is fused into gemm-1 (overlapped, not serialized)
    hipMemsetAsync(counts, 0, 2 * N_NODES * sizeof(int), stream);  // counts + cursor
    wcast_kernel<<<dim3(16, 2), 256, 0, stream>>>(W0, W1, wt0, wt1);

    // ---- layer-1 GEMM + histogram (A from fp32 x; hist atomics overlap GEMM)
    mfma_gemm<1, 1><<<ggrid, 512, 0, stream>>>(nullptr, x, wt0, al0, ar0,
                                               feat16, el, er, dst, counts);

    // ---- CSR scan + scatter (hist results ready after gemm-1 completes)
    scan_local<<<SCAN_NB, 256, 0, stream>>>(counts, offs, bsum, N_NODES);
    scan_bsum<<<1, 64, 0, stream>>>(bsum, offs, SCAN_NB, N_NODES);
    scan_add<<<SCAN_NB, 256, 0, stream>>>(offs, bsum, N_NODES);
    scatter_kernel<<<(N_EDGES + 255) / 256, 256, 0, stream>>>(src, dst, offs, cursor, csr_src, N_EDGES);

    // ---- layer 1 aggregate (h1 fp16 written into d_out)
    agg_fused<<<N_NODES / 4, 256, 0, stream>>>(feat16, el, er, b0, offs, csr_src,
                                               out, h1, 0);

    // ---- layer 2 (reads h1 fp16; final head-major fp32 write to d_out)
    mfma_gemm<0, 0><<<ggrid, 512, 0, stream>>>(h1, nullptr, wt1, al1, ar1,
                                               feat16, el, er, nullptr, nullptr);
    agg_fused<<<N_NODES / 4, 256, 0, stream>>>(feat16, el, er, b1, offs, csr_src,
                                               out, h1, 1);
}

// Round 11
// 366.793 us; speedup vs baseline: 1.0812x; 1.0016x over previous
//
#include <hip/hip_runtime.h>
#include <math.h>

#define N_NODES 50000
#define N_EDGES 800000
#define HEADS 4
#define HID 64
#define FDIM 256      // HEADS*HID == F_IN == 256 for both layers
#define SCAN_CHUNK 1024
#define SCAN_NB ((N_NODES + SCAN_CHUNK - 1) / SCAN_CHUNK)   // 49

typedef __attribute__((ext_vector_type(8))) _Float16 half8;
typedef __attribute__((ext_vector_type(4))) _Float16 half4;
typedef __attribute__((ext_vector_type(4))) float f32x4;

__device__ __forceinline__ void gload_lds16(const void* g, void* l) {
    __builtin_amdgcn_global_load_lds((const __attribute__((address_space(1))) void*)g,
                                     (__attribute__((address_space(3))) void*)l, 16, 0, 0);
}

// ---------------------------------------------------------------- CSR build
// R6: no grid.sync fusion (~100us/sync). R8: dispatch-count reduction per se
// buys nothing — only fuse work that OVERLAPS (hist inside gemm-1).

__global__ __launch_bounds__(256) void scan_local(const int* __restrict__ counts,
                                                  int* __restrict__ offs,
                                                  int* __restrict__ bsum, int n) {
    __shared__ int part[256];
    const int b = blockIdx.x, t = threadIdx.x;
    const int base = b * SCAN_CHUNK + t * 4;
    int v[4];
#pragma unroll
    for (int j = 0; j < 4; j++) {
        int idx = base + j;
        v[j] = (idx < n) ? counts[idx] : 0;
    }
    int s0 = v[0], s1 = s0 + v[1], s2 = s1 + v[2], s3 = s2 + v[3];
    part[t] = s3;
    __syncthreads();
    for (int off = 1; off < 256; off <<= 1) {
        int x = (t >= off) ? part[t - off] : 0;
        __syncthreads();
        part[t] += x;
        __syncthreads();
    }
    int prefix = (t > 0) ? part[t - 1] : 0;
    int e[4] = {prefix, prefix + s0, prefix + s1, prefix + s2};
#pragma unroll
    for (int j = 0; j < 4; j++) {
        int idx = base + j;
        if (idx < n) offs[idx] = e[j];
    }
    if (t == 255) bsum[b] = part[255];
}

__global__ __launch_bounds__(64) void scan_bsum(int* __restrict__ bsum,
                                                int* __restrict__ offs, int nb, int n) {
    int lane = threadIdx.x;
    int own = (lane < nb) ? bsum[lane] : 0;
    int v = own;
    for (int off = 1; off < 64; off <<= 1) {
        int x = __shfl_up(v, off);
        if (lane >= off) v += x;
    }
    if (lane < nb) bsum[lane] = v - own;   // exclusive prefix
    if (lane == nb - 1) offs[n] = v;       // grand total
}

__global__ __launch_bounds__(256) void scan_add(int* __restrict__ offs,
                                                const int* __restrict__ bsum, int n) {
    const int b = blockIdx.x;
    const int p = bsum[b];
    const int base = b * SCAN_CHUNK + threadIdx.x * 4;
#pragma unroll
    for (int j = 0; j < 4; j++) {
        int idx = base + j;
        if (idx < n) offs[idx] += p;
    }
}

__global__ __launch_bounds__(256) void scatter_kernel(const int* __restrict__ src,
                                                      const int* __restrict__ dst,
                                                      const int* __restrict__ offs,
                                                      int* __restrict__ cursor,
                                                      int* __restrict__ csr_src, int E) {
    int i = blockIdx.x * blockDim.x + threadIdx.x;
    if (i < E) {
        int d = dst[i];
        int p = offs[d] + atomicAdd(&cursor[d], 1);
        csr_src[p] = src[i];
    }
}

// -------------------------------------------- prep: W transpose-cast

__global__ __launch_bounds__(256) void wcast_kernel(const float* __restrict__ W0,
                                                    const float* __restrict__ W1,
                                                    _Float16* __restrict__ wt0,
                                                    _Float16* __restrict__ wt1) {
    const float* W = blockIdx.y ? W1 : W0;
    _Float16* wt = blockIdx.y ? wt1 : wt0;
    int n = blockIdx.x * 16 + (threadIdx.x >> 4);
    int k0 = (threadIdx.x & 15) * 16;
    for (int j = 0; j < 16; j++)
        wt[n * FDIM + k0 + j] = (_Float16)W[(k0 + j) * FDIM + n];
}

// -------------------------------------------- fp16 MFMA GEMM + fused el/er
// v8: Little's-law fix. R10 counters (MfmaUtil 3.5%, VALU 4.5%, 1.2 TB/s
// memory rate with nothing busy) showed the GEMM bound by bytes-in-flight:
// the 2-barrier K-step drained vmcnt before compute. Now: double-buffered
// LDS; loads for step k+1 are ISSUED (global_load_lds, no reg round-trip)
// before consuming step k, and drain at the single end-of-step barrier —
// latency hides under ds_read+MFMA. LDS swizzle kept by pre-permuting the
// per-lane GLOBAL source slot (linear LDS dest + swizzled read, rule #21).
// Layer-1 A (fp32) is register-staged: load at step top, cvt+ds_write after
// MFMA (T14 split). BM=64, 782 blocks, 512 threads / 8 waves, 32x64/wave.
// Hist fused in prologue (DO_HIST).
template <int A32, int DO_HIST>
__global__ __launch_bounds__(512) void mfma_gemm(const _Float16* __restrict__ A16,
                                                 const float* __restrict__ Af,
                                                 const _Float16* __restrict__ Bt,
                                                 const float* __restrict__ al,
                                                 const float* __restrict__ ar,
                                                 _Float16* __restrict__ feat16,
                                                 float* __restrict__ el,
                                                 float* __restrict__ er,
                                                 const int* __restrict__ dst,
                                                 int* __restrict__ counts) {
    __shared__ _Float16 ash[2][64 * 32];    // 2 x 4 KB
    __shared__ _Float16 bsh[2][256 * 32];   // 2 x 16 KB

    const int t = threadIdx.x;
    const int m0 = blockIdx.x * 64;
    const int wave = t >> 6, lane = t & 63;
    const int quad = lane >> 4, l16 = lane & 15;
    const int wr = (wave >> 2) * 32;     // rowband: 0 or 32
    const int wc = (wave & 3) * 64;      // colband: 0/64/128/192 (== head*64)

    if (DO_HIST) {
        for (int i = blockIdx.x * 512 + t; i < N_EDGES; i += gridDim.x * 512)
            atomicAdd(&counts[dst[i]], 1);
    }

    // ---- A reg-staging geometry (A32 path): thread -> one float4 of the tile
    const int arow = t >> 3, aq4 = t & 7;                  // 64 rows x 8 slots
    const int agr = (m0 + arow < N_NODES) ? m0 + arow : N_NODES - 1;
    const int aswz = (aq4 >> 1) ^ (arow & 3) ^ ((arow >> 2) & 3);
    const int aoff = arow * 32 + aswz * 8 + (aq4 & 1) * 4; // halves

    // ---- B gload geometry: wave handles 2 chunks of 64 x 16B
    // unit u -> row=u>>2, slot=u&3; source slot pre-swizzled so that the
    // swizzled READ below sees global slot 'quad' of each row.
    // ---- A16 gload geometry (layer 2): waves 0..3, 1 chunk each.

    const f32x4 zero = {0.f, 0.f, 0.f, 0.f};
    f32x4 acc[2][4];
#pragma unroll
    for (int i = 0; i < 2; i++)
#pragma unroll
        for (int j = 0; j < 4; j++) acc[i][j] = zero;

    const int rslot = (quad ^ (l16 & 3) ^ (l16 >> 2)) * 8;   // read slot (halves)

    float4 areg;

    // ---------------- prologue: stage step 0 into buffer 0
    if (A32) {
        const float* p = &Af[(size_t)agr * FDIM + aq4 * 4];
        float4 f0 = *(const float4*)p;
        half4 hv = {(_Float16)f0.x, (_Float16)f0.y, (_Float16)f0.z, (_Float16)f0.w};
        *(half4*)&ash[0][aoff] = hv;
    } else {
        if (wave < 4) {
            int u = wave * 64 + lane;
            int row = u >> 2, sl = u & 3;
            int ss = sl ^ (row & 3) ^ ((row >> 2) & 3);
            int gr = (m0 + row < N_NODES) ? m0 + row : N_NODES - 1;
            gload_lds16(&A16[(size_t)gr * FDIM + ss * 8], &ash[0][u * 8]);
        }
    }
#pragma unroll
    for (int ii = 0; ii < 2; ii++) {
        int u = (wave * 2 + ii) * 64 + lane;
        int row = u >> 2, sl = u & 3;
        int ss = sl ^ (row & 3) ^ ((row >> 2) & 3);
        gload_lds16(&Bt[(size_t)row * FDIM + ss * 8], &bsh[0][u * 8]);
    }
    __syncthreads();

    // ---------------- main loop: 8 K-steps, one barrier each
    for (int ks = 0; ks < 8; ks++) {
        const int cur = ks & 1, nxt = cur ^ 1;
        const int kk2 = (ks + 1) * 32;
        const bool pf = (ks < 7);

        // ---- issue prefetch for step ks+1 (fire-and-forget until barrier)
        if (pf) {
            if (A32) {
                areg = *(const float4*)&Af[(size_t)agr * FDIM + kk2 + aq4 * 4];
            } else {
                if (wave < 4) {
                    int u = wave * 64 + lane;
                    int row = u >> 2, sl = u & 3;
                    int ss = sl ^ (row & 3) ^ ((row >> 2) & 3);
                    int gr = (m0 + row < N_NODES) ? m0 + row : N_NODES - 1;
                    gload_lds16(&A16[(size_t)gr * FDIM + kk2 + ss * 8], &ash[nxt][u * 8]);
                }
            }
#pragma unroll
            for (int ii = 0; ii < 2; ii++) {
                int u = (wave * 2 + ii) * 64 + lane;
                int row = u >> 2, sl = u & 3;
                int ss = sl ^ (row & 3) ^ ((row >> 2) & 3);
                gload_lds16(&Bt[(size_t)row * FDIM + kk2 + ss * 8], &bsh[nxt][u * 8]);
            }
        }

        // ---- consume current buffer
        half8 af[2], bf[4];
#pragma unroll
        for (int i = 0; i < 2; i++)
            af[i] = *(half8*)&ash[cur][(wr + i * 16 + l16) * 32 + rslot];
#pragma unroll
        for (int i = 0; i < 4; i++)
            bf[i] = *(half8*)&bsh[cur][(wc + i * 16 + l16) * 32 + rslot];

        // swapped operands: C fragment transposed (l16 = m-row, quad*4+r = n-col)
#pragma unroll
        for (int mt = 0; mt < 2; mt++)
#pragma unroll
            for (int nt = 0; nt < 4; nt++)
                acc[mt][nt] = __builtin_amdgcn_mfma_f32_16x16x32_f16(bf[nt], af[mt], acc[mt][nt], 0, 0, 0);

        // ---- late half of the A32 prefetch: cvt + LDS write (waits its loads)
        if (A32 && pf) {
            half4 hv = {(_Float16)areg.x, (_Float16)areg.y, (_Float16)areg.z, (_Float16)areg.w};
            *(half4*)&ash[nxt][aoff] = hv;
        }
        if (pf) __syncthreads();   // drains gload_lds + ds_writes: next buffer ready
    }

    // ---- epilogue: vector feat16 store + fused el/er (this wave's head = h)
    const int h = wc >> 6;
    float4 alv[4], arv[4];
#pragma unroll
    for (int nt = 0; nt < 4; nt++) {
        alv[nt] = *(const float4*)&al[wc + nt * 16 + quad * 4];
        arv[nt] = *(const float4*)&ar[wc + nt * 16 + quad * 4];
    }
#pragma unroll
    for (int mt = 0; mt < 2; mt++) {
        const int m = m0 + wr + mt * 16 + l16;
        const bool ok = (m < N_NODES);
        float pl = 0.f, pr = 0.f;
#pragma unroll
        for (int nt = 0; nt < 4; nt++) {
            f32x4 v = acc[mt][nt];
            if (ok) {
                half4 hv = {(_Float16)v[0], (_Float16)v[1], (_Float16)v[2], (_Float16)v[3]};
                *(half4*)&feat16[(size_t)m * FDIM + wc + nt * 16 + quad * 4] = hv;
            }
            pl += v[0] * alv[nt].x + v[1] * alv[nt].y + v[2] * alv[nt].z + v[3] * alv[nt].w;
            pr += v[0] * arv[nt].x + v[1] * arv[nt].y + v[2] * arv[nt].z + v[3] * arv[nt].w;
        }
        pl += __shfl_xor(pl, 16);
        pl += __shfl_xor(pl, 32);
        pr += __shfl_xor(pr, 16);
        pr += __shfl_xor(pr, 32);
        if (quad == 0 && ok) {
            el[m * 4 + h] = pl;
            er[m * 4 + h] = pr;
        }
    }
}

// ------------------------------------------- fused softmax + aggregate
// Wave per node, NO LDS / NO barriers. Lane owns features f=lane*4..+3
// (head = lane>>4). v2: cooperative weights; MAC via __shfl broadcast,
// 4-wide. L2-miss-traffic-bound (~199MB @ ~3.9TB/s, L3-served) — invariant
// to scheduling (R2/R3 ablations). Single-pass softmax.
// mode 0: write h1 as fp16 (layer-2 GEMM input); mode 1: fp32 head-major.
__global__ __launch_bounds__(256) void agg_fused(const _Float16* __restrict__ feat16,
                                                 const float* __restrict__ el,
                                                 const float* __restrict__ er,
                                                 const float* __restrict__ bias,
                                                 const int* __restrict__ offs,
                                                 const int* __restrict__ csr_src,
                                                 float* __restrict__ out,
                                                 _Float16* __restrict__ h1,
                                                 int mode) {
    const int wave = threadIdx.x >> 6;
    const int lane = threadIdx.x & 63;
    const int n = blockIdx.x * 4 + wave;
    const int head = lane >> 4;
    const int f = lane * 4;           // == head*64 + (lane&15)*4
    const int base16 = lane & 48;     // first lane of this head's 16-group
    const int j16 = lane & 15;
    const int beg = offs[n];
    const int end = offs[n + 1];
    const float er_h = er[n * 4 + head];

    float4 acc = make_float4(0.f, 0.f, 0.f, 0.f);
    float ss = 0.f;

    for (int c = beg; c < end; c += 16) {
        int e = c + j16;
        int s_own = 0;
        float w_own = 0.f;
        if (e < end) {
            s_own = csr_src[e];
            float lg = el[s_own * 4 + head] + er_h;
            lg = (lg > 0.f) ? lg : 0.2f * lg;
            w_own = __expf(lg);
        }
        ss += w_own;

        int rem = end - c;
        if (rem > 16) rem = 16;

        int j = 0;
        for (; j + 3 < rem; j += 4) {
            int s0 = __shfl(s_own, base16 + j);
            int s1 = __shfl(s_own, base16 + j + 1);
            int s2 = __shfl(s_own, base16 + j + 2);
            int s3 = __shfl(s_own, base16 + j + 3);
            float w0 = __shfl(w_own, base16 + j);
            float w1 = __shfl(w_own, base16 + j + 1);
            float w2 = __shfl(w_own, base16 + j + 2);
            float w3 = __shfl(w_own, base16 + j + 3);
            half4 v0 = *(const half4*)&feat16[(size_t)s0 * FDIM + f];
            half4 v1 = *(const half4*)&feat16[(size_t)s1 * FDIM + f];
            half4 v2 = *(const half4*)&feat16[(size_t)s2 * FDIM + f];
            half4 v3 = *(const half4*)&feat16[(size_t)s3 * FDIM + f];
            acc.x += w0 * (float)v0[0] + w1 * (float)v1[0];
            acc.y += w0 * (float)v0[1] + w1 * (float)v1[1];
            acc.z += w0 * (float)v0[2] + w1 * (float)v1[2];
            acc.w += w0 * (float)v0[3] + w1 * (float)v1[3];
            acc.x += w2 * (float)v2[0] + w3 * (float)v3[0];
            acc.y += w2 * (float)v2[1] + w3 * (float)v3[1];
            acc.z += w2 * (float)v2[2] + w3 * (float)v3[2];
            acc.w += w2 * (float)v2[3] + w3 * (float)v3[3];
        }
        for (; j < rem; j++) {
            int s0 = __shfl(s_own, base16 + j);
            float w0 = __shfl(w_own, base16 + j);
            half4 v0 = *(const half4*)&feat16[(size_t)s0 * FDIM + f];
            acc.x += w0 * (float)v0[0];
            acc.y += w0 * (float)v0[1];
            acc.z += w0 * (float)v0[2];
            acc.w += w0 * (float)v0[3];
        }
    }

    ss += __shfl_xor(ss, 1, 16);
    ss += __shfl_xor(ss, 2, 16);
    ss += __shfl_xor(ss, 4, 16);
    ss += __shfl_xor(ss, 8, 16);

    float S = fmaxf(ss, 1e-9f);
    float inv = 1.f / S;
    float4 bv = *(const float4*)&bias[f];
    float r0 = acc.x * inv + bv.x;
    float r1 = acc.y * inv + bv.y;
    float r2 = acc.z * inv + bv.z;
    float r3 = acc.w * inv + bv.w;
    r0 = (r0 > 0.f) ? r0 : expm1f(r0);
    r1 = (r1 > 0.f) ? r1 : expm1f(r1);
    r2 = (r2 > 0.f) ? r2 : expm1f(r2);
    r3 = (r3 > 0.f) ? r3 : expm1f(r3);

    if (mode) {
        const int d = (lane & 15) * 4;
        float4 rv = make_float4(r0, r1, r2, r3);
        *(float4*)&out[(size_t)head * N_NODES * HID + (size_t)n * HID + d] = rv;
    } else {
        half4 hv = {(_Float16)r0, (_Float16)r1, (_Float16)r2, (_Float16)r3};
        *(half4*)&h1[(size_t)n * FDIM + f] = hv;
    }
}

// ---------------------------------------------------------------- launch

extern "C" void kernel_launch(void* const* d_in, const int* in_sizes, int n_in,
                              void* d_out, int out_size, void* d_ws, size_t ws_size,
                              hipStream_t stream) {
    const float* x   = (const float*)d_in[0];
    const int*   src = (const int*)d_in[1];
    const int*   dst = (const int*)d_in[2];
    const float* W0  = (const float*)d_in[3];
    const float* al0 = (const float*)d_in[4];
    const float* ar0 = (const float*)d_in[5];
    const float* b0  = (const float*)d_in[6];
    const float* W1  = (const float*)d_in[7];
    const float* al1 = (const float*)d_in[8];
    const float* ar1 = (const float*)d_in[9];
    const float* b1  = (const float*)d_in[10];
    float* out = (float*)d_out;

    // h1 (layer-1 hidden, fp16) lives in the first 25.6 MB of d_out.
    _Float16* h1 = (_Float16*)d_out;

    // workspace layout
    _Float16* feat16 = (_Float16*)d_ws;                          // N*256 fp16
    _Float16* wt0 = feat16 + (size_t)N_NODES * FDIM;             // 256*256
    _Float16* wt1 = wt0 + FDIM * FDIM;                           // 256*256
    float* el    = (float*)(wt1 + FDIM * FDIM);                  // N*4
    float* er    = el + N_NODES * HEADS;                         // N*4
    int* counts  = (int*)(er + N_NODES * HEADS);                 // N
    int* cursor  = counts + N_NODES;                             // N
    int* offs    = cursor + N_NODES;                             // N+1 (pad 50016)
    int* bsum    = offs + 50016;                                 // 64
    int* csr_src = bsum + 64;                                    // E

    const int ggrid = (N_NODES + 63) / 64;   // 782

    // ---- prep; hist is fused into gemm-1 (overlapped, not serialized)
    hipMemsetAsync(counts, 0, 2 * N_NODES * sizeof(int), stream);  // counts + cursor
    wcast_kernel<<<dim3(16, 2), 256, 0, stream>>>(W0, W1, wt0, wt1);

    // ---- layer-1 GEMM + histogram (A from fp32 x; hist atomics overlap GEMM)
    mfma_gemm<1, 1><<<ggrid, 512, 0, stream>>>(nullptr, x, wt0, al0, ar0,
                                               feat16, el, er, dst, counts);

    // ---- CSR scan + scatter
    scan_local<<<SCAN_NB, 256, 0, stream>>>(counts, offs, bsum, N_NODES);
    scan_bsum<<<1, 64, 0, stream>>>(bsum, offs, SCAN_NB, N_NODES);
    scan_add<<<SCAN_NB, 256, 0, stream>>>(offs, bsum, N_NODES);
    scatter_kernel<<<(N_EDGES + 255) / 256, 256, 0, stream>>>(src, dst, offs, cursor, csr_src, N_EDGES);

    // ---- layer 1 aggregate (h1 fp16 written into d_out)
    agg_fused<<<N_NODES / 4, 256, 0, stream>>>(feat16, el, er, b0, offs, csr_src,
                                               out, h1, 0);

    // ---- layer 2 (reads h1 fp16; final head-major fp32 write to d_out)
    mfma_gemm<0, 0><<<ggrid, 512, 0, stream>>>(h1, nullptr, wt1, al1, ar1,
                                               feat16, el, er, nullptr, nullptr);
    agg_fused<<<N_NODES / 4, 256, 0, stream>>>(feat16, el, er, b1, offs, csr_src,
                                               out, h1, 1);
}

// Round 12
// 361.956 us; speedup vs baseline: 1.0957x; 1.0134x over previous
//
#include <hip/hip_runtime.h>
#include <math.h>

#define N_NODES 50000
#define N_EDGES 800000
#define HEADS 4
#define HID 64
#define FDIM 256      // HEADS*HID == F_IN == 256 for both layers
#define SCAN_CHUNK 1024
#define SCAN_NB ((N_NODES + SCAN_CHUNK - 1) / SCAN_CHUNK)   // 49

typedef __attribute__((ext_vector_type(8))) _Float16 half8;
typedef __attribute__((ext_vector_type(4))) _Float16 half4;
typedef __attribute__((ext_vector_type(4))) float f32x4;

__device__ __forceinline__ void gload_lds16(const void* g, void* l) {
    __builtin_amdgcn_global_load_lds((const __attribute__((address_space(1))) void*)g,
                                     (__attribute__((address_space(3))) void*)l, 16, 0, 0);
}

// ---------------------------------------------------------------- CSR build
// R6: no grid.sync fusion (~100us/sync). R8: dispatch-count reduction per se
// buys nothing — only fuse work that OVERLAPS (hist inside gemm-1).
// R11 lesson: vmcnt is IN-ORDER — atomics issued in a prologue are drained
// by the first __syncthreads (vmcnt(0) before s_barrier), serializing the
// histogram IN FRONT of the GEMM. Hist now issues AFTER the K-loop.

__global__ __launch_bounds__(256) void scan_local(const int* __restrict__ counts,
                                                  int* __restrict__ offs,
                                                  int* __restrict__ bsum, int n) {
    __shared__ int part[256];
    const int b = blockIdx.x, t = threadIdx.x;
    const int base = b * SCAN_CHUNK + t * 4;
    int v[4];
#pragma unroll
    for (int j = 0; j < 4; j++) {
        int idx = base + j;
        v[j] = (idx < n) ? counts[idx] : 0;
    }
    int s0 = v[0], s1 = s0 + v[1], s2 = s1 + v[2], s3 = s2 + v[3];
    part[t] = s3;
    __syncthreads();
    for (int off = 1; off < 256; off <<= 1) {
        int x = (t >= off) ? part[t - off] : 0;
        __syncthreads();
        part[t] += x;
        __syncthreads();
    }
    int prefix = (t > 0) ? part[t - 1] : 0;
    int e[4] = {prefix, prefix + s0, prefix + s1, prefix + s2};
#pragma unroll
    for (int j = 0; j < 4; j++) {
        int idx = base + j;
        if (idx < n) offs[idx] = e[j];
    }
    if (t == 255) bsum[b] = part[255];
}

__global__ __launch_bounds__(64) void scan_bsum(int* __restrict__ bsum,
                                                int* __restrict__ offs, int nb, int n) {
    int lane = threadIdx.x;
    int own = (lane < nb) ? bsum[lane] : 0;
    int v = own;
    for (int off = 1; off < 64; off <<= 1) {
        int x = __shfl_up(v, off);
        if (lane >= off) v += x;
    }
    if (lane < nb) bsum[lane] = v - own;   // exclusive prefix
    if (lane == nb - 1) offs[n] = v;       // grand total
}

__global__ __launch_bounds__(256) void scan_add(int* __restrict__ offs,
                                                const int* __restrict__ bsum, int n) {
    const int b = blockIdx.x;
    const int p = bsum[b];
    const int base = b * SCAN_CHUNK + threadIdx.x * 4;
#pragma unroll
    for (int j = 0; j < 4; j++) {
        int idx = base + j;
        if (idx < n) offs[idx] += p;
    }
}

__global__ __launch_bounds__(256) void scatter_kernel(const int* __restrict__ src,
                                                      const int* __restrict__ dst,
                                                      const int* __restrict__ offs,
                                                      int* __restrict__ cursor,
                                                      int* __restrict__ csr_src, int E) {
    int i = blockIdx.x * blockDim.x + threadIdx.x;
    if (i < E) {
        int d = dst[i];
        int p = offs[d] + atomicAdd(&cursor[d], 1);
        csr_src[p] = src[i];
    }
}

// -------------------------------------------- prep: W transpose-cast

__global__ __launch_bounds__(256) void wcast_kernel(const float* __restrict__ W0,
                                                    const float* __restrict__ W1,
                                                    _Float16* __restrict__ wt0,
                                                    _Float16* __restrict__ wt1) {
    const float* W = blockIdx.y ? W1 : W0;
    _Float16* wt = blockIdx.y ? wt1 : wt0;
    int n = blockIdx.x * 16 + (threadIdx.x >> 4);
    int k0 = (threadIdx.x & 15) * 16;
    for (int j = 0; j < 16; j++)
        wt[n * FDIM + k0 + j] = (_Float16)W[(k0 + j) * FDIM + n];
}

// -------------------------------------------- fp16 MFMA GEMM + fused el/er
// v9 = v8 with hist moved to the END. R11 showed gemm-1 pinned at 67us
// regardless of schedule: the prologue hist atomics were the OLDEST vmcnt
// entries, and every __syncthreads (vmcnt(0) drain) waited for them —
// serializing ~800K cross-XCD atomics in front of the GEMM. Hist now
// issues after the last K-step (no barrier follows it; epilogue is
// barrier-free), so the atomics drain under the epilogue + kernel-end wait.
// v8: double-buffered LDS, global_load_lds staging (loads for step k+1
// issued before consuming step k), swizzle via pre-permuted GLOBAL source
// slot + swizzled read (rule #21). Layer-1 A (fp32) reg-staged with
// load-early/cvt+write-late split. BM=64, 782 blocks, 512 thr / 8 waves.
template <int A32, int DO_HIST>
__global__ __launch_bounds__(512) void mfma_gemm(const _Float16* __restrict__ A16,
                                                 const float* __restrict__ Af,
                                                 const _Float16* __restrict__ Bt,
                                                 const float* __restrict__ al,
                                                 const float* __restrict__ ar,
                                                 _Float16* __restrict__ feat16,
                                                 float* __restrict__ el,
                                                 float* __restrict__ er,
                                                 const int* __restrict__ dst,
                                                 int* __restrict__ counts) {
    __shared__ _Float16 ash[2][64 * 32];    // 2 x 4 KB
    __shared__ _Float16 bsh[2][256 * 32];   // 2 x 16 KB

    const int t = threadIdx.x;
    const int m0 = blockIdx.x * 64;
    const int wave = t >> 6, lane = t & 63;
    const int quad = lane >> 4, l16 = lane & 15;
    const int wr = (wave >> 2) * 32;     // rowband: 0 or 32
    const int wc = (wave & 3) * 64;      // colband: 0/64/128/192 (== head*64)

    // ---- A reg-staging geometry (A32 path): thread -> one float4 of the tile
    const int arow = t >> 3, aq4 = t & 7;                  // 64 rows x 8 slots
    const int agr = (m0 + arow < N_NODES) ? m0 + arow : N_NODES - 1;
    const int aswz = (aq4 >> 1) ^ (arow & 3) ^ ((arow >> 2) & 3);
    const int aoff = arow * 32 + aswz * 8 + (aq4 & 1) * 4; // halves

    const f32x4 zero = {0.f, 0.f, 0.f, 0.f};
    f32x4 acc[2][4];
#pragma unroll
    for (int i = 0; i < 2; i++)
#pragma unroll
        for (int j = 0; j < 4; j++) acc[i][j] = zero;

    const int rslot = (quad ^ (l16 & 3) ^ (l16 >> 2)) * 8;   // read slot (halves)

    float4 areg;

    // ---------------- prologue: stage step 0 into buffer 0
    if (A32) {
        const float* p = &Af[(size_t)agr * FDIM + aq4 * 4];
        float4 f0 = *(const float4*)p;
        half4 hv = {(_Float16)f0.x, (_Float16)f0.y, (_Float16)f0.z, (_Float16)f0.w};
        *(half4*)&ash[0][aoff] = hv;
    } else {
        if (wave < 4) {
            int u = wave * 64 + lane;
            int row = u >> 2, sl = u & 3;
            int ss = sl ^ (row & 3) ^ ((row >> 2) & 3);
            int gr = (m0 + row < N_NODES) ? m0 + row : N_NODES - 1;
            gload_lds16(&A16[(size_t)gr * FDIM + ss * 8], &ash[0][u * 8]);
        }
    }
#pragma unroll
    for (int ii = 0; ii < 2; ii++) {
        int u = (wave * 2 + ii) * 64 + lane;
        int row = u >> 2, sl = u & 3;
        int ss = sl ^ (row & 3) ^ ((row >> 2) & 3);
        gload_lds16(&Bt[(size_t)row * FDIM + ss * 8], &bsh[0][u * 8]);
    }
    __syncthreads();

    // ---------------- main loop: 8 K-steps, one barrier each
    for (int ks = 0; ks < 8; ks++) {
        const int cur = ks & 1, nxt = cur ^ 1;
        const int kk2 = (ks + 1) * 32;
        const bool pf = (ks < 7);

        // ---- issue prefetch for step ks+1 (fire-and-forget until barrier)
        if (pf) {
            if (A32) {
                areg = *(const float4*)&Af[(size_t)agr * FDIM + kk2 + aq4 * 4];
            } else {
                if (wave < 4) {
                    int u = wave * 64 + lane;
                    int row = u >> 2, sl = u & 3;
                    int ss = sl ^ (row & 3) ^ ((row >> 2) & 3);
                    int gr = (m0 + row < N_NODES) ? m0 + row : N_NODES - 1;
                    gload_lds16(&A16[(size_t)gr * FDIM + kk2 + ss * 8], &ash[nxt][u * 8]);
                }
            }
#pragma unroll
            for (int ii = 0; ii < 2; ii++) {
                int u = (wave * 2 + ii) * 64 + lane;
                int row = u >> 2, sl = u & 3;
                int ss = sl ^ (row & 3) ^ ((row >> 2) & 3);
                gload_lds16(&Bt[(size_t)row * FDIM + kk2 + ss * 8], &bsh[nxt][u * 8]);
            }
        }

        // ---- consume current buffer
        half8 af[2], bf[4];
#pragma unroll
        for (int i = 0; i < 2; i++)
            af[i] = *(half8*)&ash[cur][(wr + i * 16 + l16) * 32 + rslot];
#pragma unroll
        for (int i = 0; i < 4; i++)
            bf[i] = *(half8*)&bsh[cur][(wc + i * 16 + l16) * 32 + rslot];

        // swapped operands: C fragment transposed (l16 = m-row, quad*4+r = n-col)
#pragma unroll
        for (int mt = 0; mt < 2; mt++)
#pragma unroll
            for (int nt = 0; nt < 4; nt++)
                acc[mt][nt] = __builtin_amdgcn_mfma_f32_16x16x32_f16(bf[nt], af[mt], acc[mt][nt], 0, 0, 0);

        // ---- late half of the A32 prefetch: cvt + LDS write (waits its loads)
        if (A32 && pf) {
            half4 hv = {(_Float16)areg.x, (_Float16)areg.y, (_Float16)areg.z, (_Float16)areg.w};
            *(half4*)&ash[nxt][aoff] = hv;
        }
        if (pf) __syncthreads();   // drains gload_lds + ds_writes: next buffer ready
    }

    // ---- histogram (AFTER all barriers): atomics drain under the epilogue
    // and the end-of-kernel wait, never blocking a __syncthreads.
    if (DO_HIST) {
        for (int i = blockIdx.x * 512 + t; i < N_EDGES; i += gridDim.x * 512)
            atomicAdd(&counts[dst[i]], 1);
    }

    // ---- epilogue: vector feat16 store + fused el/er (this wave's head = h)
    const int h = wc >> 6;
    float4 alv[4], arv[4];
#pragma unroll
    for (int nt = 0; nt < 4; nt++) {
        alv[nt] = *(const float4*)&al[wc + nt * 16 + quad * 4];
        arv[nt] = *(const float4*)&ar[wc + nt * 16 + quad * 4];
    }
#pragma unroll
    for (int mt = 0; mt < 2; mt++) {
        const int m = m0 + wr + mt * 16 + l16;
        const bool ok = (m < N_NODES);
        float pl = 0.f, pr = 0.f;
#pragma unroll
        for (int nt = 0; nt < 4; nt++) {
            f32x4 v = acc[mt][nt];
            if (ok) {
                half4 hv = {(_Float16)v[0], (_Float16)v[1], (_Float16)v[2], (_Float16)v[3]};
                *(half4*)&feat16[(size_t)m * FDIM + wc + nt * 16 + quad * 4] = hv;
            }
            pl += v[0] * alv[nt].x + v[1] * alv[nt].y + v[2] * alv[nt].z + v[3] * alv[nt].w;
            pr += v[0] * arv[nt].x + v[1] * arv[nt].y + v[2] * arv[nt].z + v[3] * arv[nt].w;
        }
        pl += __shfl_xor(pl, 16);
        pl += __shfl_xor(pl, 32);
        pr += __shfl_xor(pr, 16);
        pr += __shfl_xor(pr, 32);
        if (quad == 0 && ok) {
            el[m * 4 + h] = pl;
            er[m * 4 + h] = pr;
        }
    }
}

// ------------------------------------------- fused softmax + aggregate
// Wave per node, NO LDS / NO barriers. Lane owns features f=lane*4..+3
// (head = lane>>4). v2: cooperative weights; MAC via __shfl broadcast,
// 4-wide. L2-miss-traffic-bound (~199MB @ ~3.9TB/s, L3-served) — invariant
// to scheduling (R2/R3 ablations). Single-pass softmax.
// mode 0: write h1 as fp16 (layer-2 GEMM input); mode 1: fp32 head-major.
__global__ __launch_bounds__(256) void agg_fused(const _Float16* __restrict__ feat16,
                                                 const float* __restrict__ el,
                                                 const float* __restrict__ er,
                                                 const float* __restrict__ bias,
                                                 const int* __restrict__ offs,
                                                 const int* __restrict__ csr_src,
                                                 float* __restrict__ out,
                                                 _Float16* __restrict__ h1,
                                                 int mode) {
    const int wave = threadIdx.x >> 6;
    const int lane = threadIdx.x & 63;
    const int n = blockIdx.x * 4 + wave;
    const int head = lane >> 4;
    const int f = lane * 4;           // == head*64 + (lane&15)*4
    const int base16 = lane & 48;     // first lane of this head's 16-group
    const int j16 = lane & 15;
    const int beg = offs[n];
    const int end = offs[n + 1];
    const float er_h = er[n * 4 + head];

    float4 acc = make_float4(0.f, 0.f, 0.f, 0.f);
    float ss = 0.f;

    for (int c = beg; c < end; c += 16) {
        int e = c + j16;
        int s_own = 0;
        float w_own = 0.f;
        if (e < end) {
            s_own = csr_src[e];
            float lg = el[s_own * 4 + head] + er_h;
            lg = (lg > 0.f) ? lg : 0.2f * lg;
            w_own = __expf(lg);
        }
        ss += w_own;

        int rem = end - c;
        if (rem > 16) rem = 16;

        int j = 0;
        for (; j + 3 < rem; j += 4) {
            int s0 = __shfl(s_own, base16 + j);
            int s1 = __shfl(s_own, base16 + j + 1);
            int s2 = __shfl(s_own, base16 + j + 2);
            int s3 = __shfl(s_own, base16 + j + 3);
            float w0 = __shfl(w_own, base16 + j);
            float w1 = __shfl(w_own, base16 + j + 1);
            float w2 = __shfl(w_own, base16 + j + 2);
            float w3 = __shfl(w_own, base16 + j + 3);
            half4 v0 = *(const half4*)&feat16[(size_t)s0 * FDIM + f];
            half4 v1 = *(const half4*)&feat16[(size_t)s1 * FDIM + f];
            half4 v2 = *(const half4*)&feat16[(size_t)s2 * FDIM + f];
            half4 v3 = *(const half4*)&feat16[(size_t)s3 * FDIM + f];
            acc.x += w0 * (float)v0[0] + w1 * (float)v1[0];
            acc.y += w0 * (float)v0[1] + w1 * (float)v1[1];
            acc.z += w0 * (float)v0[2] + w1 * (float)v1[2];
            acc.w += w0 * (float)v0[3] + w1 * (float)v1[3];
            acc.x += w2 * (float)v2[0] + w3 * (float)v3[0];
            acc.y += w2 * (float)v2[1] + w3 * (float)v3[1];
            acc.z += w2 * (float)v2[2] + w3 * (float)v3[2];
            acc.w += w2 * (float)v2[3] + w3 * (float)v3[3];
        }
        for (; j < rem; j++) {
            int s0 = __shfl(s_own, base16 + j);
            float w0 = __shfl(w_own, base16 + j);
            half4 v0 = *(const half4*)&feat16[(size_t)s0 * FDIM + f];
            acc.x += w0 * (float)v0[0];
            acc.y += w0 * (float)v0[1];
            acc.z += w0 * (float)v0[2];
            acc.w += w0 * (float)v0[3];
        }
    }

    ss += __shfl_xor(ss, 1, 16);
    ss += __shfl_xor(ss, 2, 16);
    ss += __shfl_xor(ss, 4, 16);
    ss += __shfl_xor(ss, 8, 16);

    float S = fmaxf(ss, 1e-9f);
    float inv = 1.f / S;
    float4 bv = *(const float4*)&bias[f];
    float r0 = acc.x * inv + bv.x;
    float r1 = acc.y * inv + bv.y;
    float r2 = acc.z * inv + bv.z;
    float r3 = acc.w * inv + bv.w;
    r0 = (r0 > 0.f) ? r0 : expm1f(r0);
    r1 = (r1 > 0.f) ? r1 : expm1f(r1);
    r2 = (r2 > 0.f) ? r2 : expm1f(r2);
    r3 = (r3 > 0.f) ? r3 : expm1f(r3);

    if (mode) {
        const int d = (lane & 15) * 4;
        float4 rv = make_float4(r0, r1, r2, r3);
        *(float4*)&out[(size_t)head * N_NODES * HID + (size_t)n * HID + d] = rv;
    } else {
        half4 hv = {(_Float16)r0, (_Float16)r1, (_Float16)r2, (_Float16)r3};
        *(half4*)&h1[(size_t)n * FDIM + f] = hv;
    }
}

// ---------------------------------------------------------------- launch

extern "C" void kernel_launch(void* const* d_in, const int* in_sizes, int n_in,
                              void* d_out, int out_size, void* d_ws, size_t ws_size,
                              hipStream_t stream) {
    const float* x   = (const float*)d_in[0];
    const int*   src = (const int*)d_in[1];
    const int*   dst = (const int*)d_in[2];
    const float* W0  = (const float*)d_in[3];
    const float* al0 = (const float*)d_in[4];
    const float* ar0 = (const float*)d_in[5];
    const float* b0  = (const float*)d_in[6];
    const float* W1  = (const float*)d_in[7];
    const float* al1 = (const float*)d_in[8];
    const float* ar1 = (const float*)d_in[9];
    const float* b1  = (const float*)d_in[10];
    float* out = (float*)d_out;

    // h1 (layer-1 hidden, fp16) lives in the first 25.6 MB of d_out.
    _Float16* h1 = (_Float16*)d_out;

    // workspace layout
    _Float16* feat16 = (_Float16*)d_ws;                          // N*256 fp16
    _Float16* wt0 = feat16 + (size_t)N_NODES * FDIM;             // 256*256
    _Float16* wt1 = wt0 + FDIM * FDIM;                           // 256*256
    float* el    = (float*)(wt1 + FDIM * FDIM);                  // N*4
    float* er    = el + N_NODES * HEADS;                         // N*4
    int* counts  = (int*)(er + N_NODES * HEADS);                 // N
    int* cursor  = counts + N_NODES;                             // N
    int* offs    = cursor + N_NODES;                             // N+1 (pad 50016)
    int* bsum    = offs + 50016;                                 // 64
    int* csr_src = bsum + 64;                                    // E

    const int ggrid = (N_NODES + 63) / 64;   // 782

    // ---- prep; hist is fused into gemm-1's TAIL (overlapped, not serialized)
    hipMemsetAsync(counts, 0, 2 * N_NODES * sizeof(int), stream);  // counts + cursor
    wcast_kernel<<<dim3(16, 2), 256, 0, stream>>>(W0, W1, wt0, wt1);

    // ---- layer-1 GEMM + histogram (A from fp32 x)
    mfma_gemm<1, 1><<<ggrid, 512, 0, stream>>>(nullptr, x, wt0, al0, ar0,
                                               feat16, el, er, dst, counts);

    // ---- CSR scan + scatter
    scan_local<<<SCAN_NB, 256, 0, stream>>>(counts, offs, bsum, N_NODES);
    scan_bsum<<<1, 64, 0, stream>>>(bsum, offs, SCAN_NB, N_NODES);
    scan_add<<<SCAN_NB, 256, 0, stream>>>(offs, bsum, N_NODES);
    scatter_kernel<<<(N_EDGES + 255) / 256, 256, 0, stream>>>(src, dst, offs, cursor, csr_src, N_EDGES);

    // ---- layer 1 aggregate (h1 fp16 written into d_out)
    agg_fused<<<N_NODES / 4, 256, 0, stream>>>(feat16, el, er, b0, offs, csr_src,
                                               out, h1, 0);

    // ---- layer 2 (reads h1 fp16; final head-major fp32 write to d_out)
    mfma_gemm<0, 0><<<ggrid, 512, 0, stream>>>(h1, nullptr, wt1, al1, ar1,
                                               feat16, el, er, nullptr, nullptr);
    agg_fused<<<N_NODES / 4, 256, 0, stream>>>(feat16, el, er, b1, offs, csr_src,
                                               out, h1, 1);
}

// Round 13
// 343.739 us; speedup vs baseline: 1.1537x; 1.0530x over previous
//
#include <hip/hip_runtime.h>
#include <math.h>

#define N_NODES 50000
#define N_EDGES 800000
#define HEADS 4
#define HID 64
#define FDIM 256      // HEADS*HID == F_IN == 256 for both layers
#define SCAN_CHUNK 1024
#define SCAN_NB ((N_NODES + SCAN_CHUNK - 1) / SCAN_CHUNK)   // 49

typedef __attribute__((ext_vector_type(8))) _Float16 half8;
typedef __attribute__((ext_vector_type(4))) _Float16 half4;
typedef __attribute__((ext_vector_type(4))) float f32x4;

__device__ __forceinline__ void gload_lds16(const void* g, void* l) {
    __builtin_amdgcn_global_load_lds((const __attribute__((address_space(1))) void*)g,
                                     (__attribute__((address_space(3))) void*)l, 16, 0, 0);
}

// ---------------------------------------------------------------- CSR build
// R6: no grid.sync fusion (~100us/sync). R8: dispatch-count reduction per se
// buys nothing. R11/R12: 800K device-scope atomics are THROUGHPUT-limited
// (~40-50us) regardless of placement — so run the atomic pass ONCE:
// the fused hist captures atomicAdd's return as the edge's in-segment rank,
// and scatter becomes atomic-free (offs[d] + rank[i]).

__global__ __launch_bounds__(256) void scan_local(const int* __restrict__ counts,
                                                  int* __restrict__ offs,
                                                  int* __restrict__ bsum, int n) {
    __shared__ int part[256];
    const int b = blockIdx.x, t = threadIdx.x;
    const int base = b * SCAN_CHUNK + t * 4;
    int v[4];
#pragma unroll
    for (int j = 0; j < 4; j++) {
        int idx = base + j;
        v[j] = (idx < n) ? counts[idx] : 0;
    }
    int s0 = v[0], s1 = s0 + v[1], s2 = s1 + v[2], s3 = s2 + v[3];
    part[t] = s3;
    __syncthreads();
    for (int off = 1; off < 256; off <<= 1) {
        int x = (t >= off) ? part[t - off] : 0;
        __syncthreads();
        part[t] += x;
        __syncthreads();
    }
    int prefix = (t > 0) ? part[t - 1] : 0;
    int e[4] = {prefix, prefix + s0, prefix + s1, prefix + s2};
#pragma unroll
    for (int j = 0; j < 4; j++) {
        int idx = base + j;
        if (idx < n) offs[idx] = e[j];
    }
    if (t == 255) bsum[b] = part[255];
}

__global__ __launch_bounds__(64) void scan_bsum(int* __restrict__ bsum,
                                                int* __restrict__ offs, int nb, int n) {
    int lane = threadIdx.x;
    int own = (lane < nb) ? bsum[lane] : 0;
    int v = own;
    for (int off = 1; off < 64; off <<= 1) {
        int x = __shfl_up(v, off);
        if (lane >= off) v += x;
    }
    if (lane < nb) bsum[lane] = v - own;   // exclusive prefix
    if (lane == nb - 1) offs[n] = v;       // grand total
}

__global__ __launch_bounds__(256) void scan_add(int* __restrict__ offs,
                                                const int* __restrict__ bsum, int n) {
    const int b = blockIdx.x;
    const int p = bsum[b];
    const int base = b * SCAN_CHUNK + threadIdx.x * 4;
#pragma unroll
    for (int j = 0; j < 4; j++) {
        int idx = base + j;
        if (idx < n) offs[idx] += p;
    }
}

// atomic-free scatter: rank captured during the (single) atomic hist pass
__global__ __launch_bounds__(256) void scatter_kernel(const int* __restrict__ src,
                                                      const int* __restrict__ dst,
                                                      const int* __restrict__ offs,
                                                      const int* __restrict__ rank,
                                                      int* __restrict__ csr_src, int E) {
    int i = blockIdx.x * blockDim.x + threadIdx.x;
    if (i < E) {
        int d = dst[i];
        csr_src[offs[d] + rank[i]] = src[i];
    }
}

// -------------------------------------------- prep: W transpose-cast

__global__ __launch_bounds__(256) void wcast_kernel(const float* __restrict__ W0,
                                                    const float* __restrict__ W1,
                                                    _Float16* __restrict__ wt0,
                                                    _Float16* __restrict__ wt1) {
    const float* W = blockIdx.y ? W1 : W0;
    _Float16* wt = blockIdx.y ? wt1 : wt0;
    int n = blockIdx.x * 16 + (threadIdx.x >> 4);
    int k0 = (threadIdx.x & 15) * 16;
    for (int j = 0; j < 16; j++)
        wt[n * FDIM + k0 + j] = (_Float16)W[(k0 + j) * FDIM + n];
}

// -------------------------------------------- fp16 MFMA GEMM + fused el/er
// v10 = v9 + rank-capturing hist (single atomic pass for the whole CSR
// build). Hist sits after the last K-step (R11: vmcnt is in-order; atomics
// before a barrier serialize in front of the GEMM); its atomics+rank-writes
// drain under the epilogue and kernel-end wait.
// v8 core: double-buffered LDS, global_load_lds staging (step k+1 issued
// before consuming step k), swizzle via pre-permuted GLOBAL source slot +
// swizzled read. Layer-1 A (fp32) reg-staged load-early/cvt-late.
// BM=64, 782 blocks, 512 thr / 8 waves, 32x64 per wave.
template <int A32, int DO_HIST>
__global__ __launch_bounds__(512) void mfma_gemm(const _Float16* __restrict__ A16,
                                                 const float* __restrict__ Af,
                                                 const _Float16* __restrict__ Bt,
                                                 const float* __restrict__ al,
                                                 const float* __restrict__ ar,
                                                 _Float16* __restrict__ feat16,
                                                 float* __restrict__ el,
                                                 float* __restrict__ er,
                                                 const int* __restrict__ dst,
                                                 int* __restrict__ counts,
                                                 int* __restrict__ rank) {
    __shared__ _Float16 ash[2][64 * 32];    // 2 x 4 KB
    __shared__ _Float16 bsh[2][256 * 32];   // 2 x 16 KB

    const int t = threadIdx.x;
    const int m0 = blockIdx.x * 64;
    const int wave = t >> 6, lane = t & 63;
    const int quad = lane >> 4, l16 = lane & 15;
    const int wr = (wave >> 2) * 32;     // rowband: 0 or 32
    const int wc = (wave & 3) * 64;      // colband: 0/64/128/192 (== head*64)

    // ---- A reg-staging geometry (A32 path): thread -> one float4 of the tile
    const int arow = t >> 3, aq4 = t & 7;                  // 64 rows x 8 slots
    const int agr = (m0 + arow < N_NODES) ? m0 + arow : N_NODES - 1;
    const int aswz = (aq4 >> 1) ^ (arow & 3) ^ ((arow >> 2) & 3);
    const int aoff = arow * 32 + aswz * 8 + (aq4 & 1) * 4; // halves

    const f32x4 zero = {0.f, 0.f, 0.f, 0.f};
    f32x4 acc[2][4];
#pragma unroll
    for (int i = 0; i < 2; i++)
#pragma unroll
        for (int j = 0; j < 4; j++) acc[i][j] = zero;

    const int rslot = (quad ^ (l16 & 3) ^ (l16 >> 2)) * 8;   // read slot (halves)

    float4 areg;

    // ---------------- prologue: stage step 0 into buffer 0
    if (A32) {
        const float* p = &Af[(size_t)agr * FDIM + aq4 * 4];
        float4 f0 = *(const float4*)p;
        half4 hv = {(_Float16)f0.x, (_Float16)f0.y, (_Float16)f0.z, (_Float16)f0.w};
        *(half4*)&ash[0][aoff] = hv;
    } else {
        if (wave < 4) {
            int u = wave * 64 + lane;
            int row = u >> 2, sl = u & 3;
            int ss = sl ^ (row & 3) ^ ((row >> 2) & 3);
            int gr = (m0 + row < N_NODES) ? m0 + row : N_NODES - 1;
            gload_lds16(&A16[(size_t)gr * FDIM + ss * 8], &ash[0][u * 8]);
        }
    }
#pragma unroll
    for (int ii = 0; ii < 2; ii++) {
        int u = (wave * 2 + ii) * 64 + lane;
        int row = u >> 2, sl = u & 3;
        int ss = sl ^ (row & 3) ^ ((row >> 2) & 3);
        gload_lds16(&Bt[(size_t)row * FDIM + ss * 8], &bsh[0][u * 8]);
    }
    __syncthreads();

    // ---------------- main loop: 8 K-steps, one barrier each
    for (int ks = 0; ks < 8; ks++) {
        const int cur = ks & 1, nxt = cur ^ 1;
        const int kk2 = (ks + 1) * 32;
        const bool pf = (ks < 7);

        // ---- issue prefetch for step ks+1 (fire-and-forget until barrier)
        if (pf) {
            if (A32) {
                areg = *(const float4*)&Af[(size_t)agr * FDIM + kk2 + aq4 * 4];
            } else {
                if (wave < 4) {
                    int u = wave * 64 + lane;
                    int row = u >> 2, sl = u & 3;
                    int ss = sl ^ (row & 3) ^ ((row >> 2) & 3);
                    int gr = (m0 + row < N_NODES) ? m0 + row : N_NODES - 1;
                    gload_lds16(&A16[(size_t)gr * FDIM + kk2 + ss * 8], &ash[nxt][u * 8]);
                }
            }
#pragma unroll
            for (int ii = 0; ii < 2; ii++) {
                int u = (wave * 2 + ii) * 64 + lane;
                int row = u >> 2, sl = u & 3;
                int ss = sl ^ (row & 3) ^ ((row >> 2) & 3);
                gload_lds16(&Bt[(size_t)row * FDIM + kk2 + ss * 8], &bsh[nxt][u * 8]);
            }
        }

        // ---- consume current buffer
        half8 af[2], bf[4];
#pragma unroll
        for (int i = 0; i < 2; i++)
            af[i] = *(half8*)&ash[cur][(wr + i * 16 + l16) * 32 + rslot];
#pragma unroll
        for (int i = 0; i < 4; i++)
            bf[i] = *(half8*)&bsh[cur][(wc + i * 16 + l16) * 32 + rslot];

        // swapped operands: C fragment transposed (l16 = m-row, quad*4+r = n-col)
#pragma unroll
        for (int mt = 0; mt < 2; mt++)
#pragma unroll
            for (int nt = 0; nt < 4; nt++)
                acc[mt][nt] = __builtin_amdgcn_mfma_f32_16x16x32_f16(bf[nt], af[mt], acc[mt][nt], 0, 0, 0);

        // ---- late half of the A32 prefetch: cvt + LDS write (waits its loads)
        if (A32 && pf) {
            half4 hv = {(_Float16)areg.x, (_Float16)areg.y, (_Float16)areg.z, (_Float16)areg.w};
            *(half4*)&ash[nxt][aoff] = hv;
        }
        if (pf) __syncthreads();   // drains gload_lds + ds_writes: next buffer ready
    }

    // ---- rank-capturing histogram (AFTER all barriers): the atomicAdd
    // return value is the edge's within-dst-segment rank; scatter needs no
    // atomics. Atomics + rank stores drain under the epilogue/kernel-end.
    if (DO_HIST) {
        for (int i = blockIdx.x * 512 + t; i < N_EDGES; i += gridDim.x * 512)
            rank[i] = atomicAdd(&counts[dst[i]], 1);
    }

    // ---- epilogue: vector feat16 store + fused el/er (this wave's head = h)
    const int h = wc >> 6;
    float4 alv[4], arv[4];
#pragma unroll
    for (int nt = 0; nt < 4; nt++) {
        alv[nt] = *(const float4*)&al[wc + nt * 16 + quad * 4];
        arv[nt] = *(const float4*)&ar[wc + nt * 16 + quad * 4];
    }
#pragma unroll
    for (int mt = 0; mt < 2; mt++) {
        const int m = m0 + wr + mt * 16 + l16;
        const bool ok = (m < N_NODES);
        float pl = 0.f, pr = 0.f;
#pragma unroll
        for (int nt = 0; nt < 4; nt++) {
            f32x4 v = acc[mt][nt];
            if (ok) {
                half4 hv = {(_Float16)v[0], (_Float16)v[1], (_Float16)v[2], (_Float16)v[3]};
                *(half4*)&feat16[(size_t)m * FDIM + wc + nt * 16 + quad * 4] = hv;
            }
            pl += v[0] * alv[nt].x + v[1] * alv[nt].y + v[2] * alv[nt].z + v[3] * alv[nt].w;
            pr += v[0] * arv[nt].x + v[1] * arv[nt].y + v[2] * arv[nt].z + v[3] * arv[nt].w;
        }
        pl += __shfl_xor(pl, 16);
        pl += __shfl_xor(pl, 32);
        pr += __shfl_xor(pr, 16);
        pr += __shfl_xor(pr, 32);
        if (quad == 0 && ok) {
            el[m * 4 + h] = pl;
            er[m * 4 + h] = pr;
        }
    }
}

// ------------------------------------------- fused softmax + aggregate
// Wave per node, NO LDS / NO barriers. Lane owns features f=lane*4..+3
// (head = lane>>4). v2: cooperative weights; MAC via __shfl broadcast,
// 4-wide. L2-miss-traffic-bound (~199MB @ ~3.9TB/s, L3-served) — invariant
// to scheduling (R2/R3 ablations). Single-pass softmax.
// mode 0: write h1 as fp16 (layer-2 GEMM input); mode 1: fp32 head-major.
__global__ __launch_bounds__(256) void agg_fused(const _Float16* __restrict__ feat16,
                                                 const float* __restrict__ el,
                                                 const float* __restrict__ er,
                                                 const float* __restrict__ bias,
                                                 const int* __restrict__ offs,
                                                 const int* __restrict__ csr_src,
                                                 float* __restrict__ out,
                                                 _Float16* __restrict__ h1,
                                                 int mode) {
    const int wave = threadIdx.x >> 6;
    const int lane = threadIdx.x & 63;
    const int n = blockIdx.x * 4 + wave;
    const int head = lane >> 4;
    const int f = lane * 4;           // == head*64 + (lane&15)*4
    const int base16 = lane & 48;     // first lane of this head's 16-group
    const int j16 = lane & 15;
    const int beg = offs[n];
    const int end = offs[n + 1];
    const float er_h = er[n * 4 + head];

    float4 acc = make_float4(0.f, 0.f, 0.f, 0.f);
    float ss = 0.f;

    for (int c = beg; c < end; c += 16) {
        int e = c + j16;
        int s_own = 0;
        float w_own = 0.f;
        if (e < end) {
            s_own = csr_src[e];
            float lg = el[s_own * 4 + head] + er_h;
            lg = (lg > 0.f) ? lg : 0.2f * lg;
            w_own = __expf(lg);
        }
        ss += w_own;

        int rem = end - c;
        if (rem > 16) rem = 16;

        int j = 0;
        for (; j + 3 < rem; j += 4) {
            int s0 = __shfl(s_own, base16 + j);
            int s1 = __shfl(s_own, base16 + j + 1);
            int s2 = __shfl(s_own, base16 + j + 2);
            int s3 = __shfl(s_own, base16 + j + 3);
            float w0 = __shfl(w_own, base16 + j);
            float w1 = __shfl(w_own, base16 + j + 1);
            float w2 = __shfl(w_own, base16 + j + 2);
            float w3 = __shfl(w_own, base16 + j + 3);
            half4 v0 = *(const half4*)&feat16[(size_t)s0 * FDIM + f];
            half4 v1 = *(const half4*)&feat16[(size_t)s1 * FDIM + f];
            half4 v2 = *(const half4*)&feat16[(size_t)s2 * FDIM + f];
            half4 v3 = *(const half4*)&feat16[(size_t)s3 * FDIM + f];
            acc.x += w0 * (float)v0[0] + w1 * (float)v1[0];
            acc.y += w0 * (float)v0[1] + w1 * (float)v1[1];
            acc.z += w0 * (float)v0[2] + w1 * (float)v1[2];
            acc.w += w0 * (float)v0[3] + w1 * (float)v1[3];
            acc.x += w2 * (float)v2[0] + w3 * (float)v3[0];
            acc.y += w2 * (float)v2[1] + w3 * (float)v3[1];
            acc.z += w2 * (float)v2[2] + w3 * (float)v3[2];
            acc.w += w2 * (float)v2[3] + w3 * (float)v3[3];
        }
        for (; j < rem; j++) {
            int s0 = __shfl(s_own, base16 + j);
            float w0 = __shfl(w_own, base16 + j);
            half4 v0 = *(const half4*)&feat16[(size_t)s0 * FDIM + f];
            acc.x += w0 * (float)v0[0];
            acc.y += w0 * (float)v0[1];
            acc.z += w0 * (float)v0[2];
            acc.w += w0 * (float)v0[3];
        }
    }

    ss += __shfl_xor(ss, 1, 16);
    ss += __shfl_xor(ss, 2, 16);
    ss += __shfl_xor(ss, 4, 16);
    ss += __shfl_xor(ss, 8, 16);

    float S = fmaxf(ss, 1e-9f);
    float inv = 1.f / S;
    float4 bv = *(const float4*)&bias[f];
    float r0 = acc.x * inv + bv.x;
    float r1 = acc.y * inv + bv.y;
    float r2 = acc.z * inv + bv.z;
    float r3 = acc.w * inv + bv.w;
    r0 = (r0 > 0.f) ? r0 : expm1f(r0);
    r1 = (r1 > 0.f) ? r1 : expm1f(r1);
    r2 = (r2 > 0.f) ? r2 : expm1f(r2);
    r3 = (r3 > 0.f) ? r3 : expm1f(r3);

    if (mode) {
        const int d = (lane & 15) * 4;
        float4 rv = make_float4(r0, r1, r2, r3);
        *(float4*)&out[(size_t)head * N_NODES * HID + (size_t)n * HID + d] = rv;
    } else {
        half4 hv = {(_Float16)r0, (_Float16)r1, (_Float16)r2, (_Float16)r3};
        *(half4*)&h1[(size_t)n * FDIM + f] = hv;
    }
}

// ---------------------------------------------------------------- launch

extern "C" void kernel_launch(void* const* d_in, const int* in_sizes, int n_in,
                              void* d_out, int out_size, void* d_ws, size_t ws_size,
                              hipStream_t stream) {
    const float* x   = (const float*)d_in[0];
    const int*   src = (const int*)d_in[1];
    const int*   dst = (const int*)d_in[2];
    const float* W0  = (const float*)d_in[3];
    const float* al0 = (const float*)d_in[4];
    const float* ar0 = (const float*)d_in[5];
    const float* b0  = (const float*)d_in[6];
    const float* W1  = (const float*)d_in[7];
    const float* al1 = (const float*)d_in[8];
    const float* ar1 = (const float*)d_in[9];
    const float* b1  = (const float*)d_in[10];
    float* out = (float*)d_out;

    // h1 (layer-1 hidden, fp16) lives in the first 25.6 MB of d_out.
    _Float16* h1 = (_Float16*)d_out;

    // workspace layout
    _Float16* feat16 = (_Float16*)d_ws;                          // N*256 fp16
    _Float16* wt0 = feat16 + (size_t)N_NODES * FDIM;             // 256*256
    _Float16* wt1 = wt0 + FDIM * FDIM;                           // 256*256
    float* el    = (float*)(wt1 + FDIM * FDIM);                  // N*4
    float* er    = el + N_NODES * HEADS;                         // N*4
    int* counts  = (int*)(er + N_NODES * HEADS);                 // N
    int* offs    = counts + N_NODES;                             // N+1 (pad 50016)
    int* bsum    = offs + 50016;                                 // 64
    int* csr_src = bsum + 64;                                    // E
    int* rank    = csr_src + N_EDGES;                            // E

    const int ggrid = (N_NODES + 63) / 64;   // 782

    // ---- prep; rank-capturing hist is fused into gemm-1's TAIL
    hipMemsetAsync(counts, 0, N_NODES * sizeof(int), stream);
    wcast_kernel<<<dim3(16, 2), 256, 0, stream>>>(W0, W1, wt0, wt1);

    // ---- layer-1 GEMM + rank-capturing histogram (A from fp32 x)
    mfma_gemm<1, 1><<<ggrid, 512, 0, stream>>>(nullptr, x, wt0, al0, ar0,
                                               feat16, el, er, dst, counts, rank);

    // ---- CSR scan + atomic-free scatter
    scan_local<<<SCAN_NB, 256, 0, stream>>>(counts, offs, bsum, N_NODES);
    scan_bsum<<<1, 64, 0, stream>>>(bsum, offs, SCAN_NB, N_NODES);
    scan_add<<<SCAN_NB, 256, 0, stream>>>(offs, bsum, N_NODES);
    scatter_kernel<<<(N_EDGES + 255) / 256, 256, 0, stream>>>(src, dst, offs, rank, csr_src, N_EDGES);

    // ---- layer 1 aggregate (h1 fp16 written into d_out)
    agg_fused<<<N_NODES / 4, 256, 0, stream>>>(feat16, el, er, b0, offs, csr_src,
                                               out, h1, 0);

    // ---- layer 2 (reads h1 fp16; final head-major fp32 write to d_out)
    mfma_gemm<0, 0><<<ggrid, 512, 0, stream>>>(h1, nullptr, wt1, al1, ar1,
                                               feat16, el, er, nullptr, nullptr, nullptr);
    agg_fused<<<N_NODES / 4, 256, 0, stream>>>(feat16, el, er, b1, offs, csr_src,
                                               out, h1, 1);
}

// Round 14
// 334.504 us; speedup vs baseline: 1.1856x; 1.0276x over previous
//
#include <hip/hip_runtime.h>
#include <math.h>

#define N_NODES 50000
#define N_EDGES 800000
#define HEADS 4
#define HID 64
#define FDIM 256      // HEADS*HID == F_IN == 256 for both layers
#define SCAN_CHUNK 1024
#define SCAN_NB ((N_NODES + SCAN_CHUNK - 1) / SCAN_CHUNK)   // 49

typedef __attribute__((ext_vector_type(8))) _Float16 half8;
typedef __attribute__((ext_vector_type(4))) _Float16 half4;
typedef __attribute__((ext_vector_type(4))) float f32x4;

__device__ __forceinline__ void gload_lds16(const void* g, void* l) {
    __builtin_amdgcn_global_load_lds((const __attribute__((address_space(1))) void*)g,
                                     (__attribute__((address_space(3))) void*)l, 16, 0, 0);
}

// ---------------------------------------------------------------- prep
// wcast (blocks 0..31, per-block code identical to the old wcast_kernel) +
// counts/flags zeroing (blocks 32..44). Independent work, no sync needed.
// Replaces hipMemsetAsync + wcast_kernel (2 fewer dispatch boundaries).
__global__ __launch_bounds__(256) void prep_kernel(const float* __restrict__ W0,
                                                   const float* __restrict__ W1,
                                                   _Float16* __restrict__ wt0,
                                                   _Float16* __restrict__ wt1,
                                                   int* __restrict__ counts,
                                                   int* __restrict__ flags) {
    const int b = blockIdx.x, t = threadIdx.x;
    if (b < 32) {
        const float* W = (b >= 16) ? W1 : W0;
        _Float16* wt = (b >= 16) ? wt1 : wt0;
        int n = (b & 15) * 16 + (t >> 4);
        int k0 = (t & 15) * 16;
        for (int j = 0; j < 16; j++)
            wt[n * FDIM + k0 + j] = (_Float16)W[(k0 + j) * FDIM + n];
    } else {
        int4 z = make_int4(0, 0, 0, 0);
        int4* p = (int4*)counts;                     // 12500 int4
        for (int k = (b - 32) * 256 + t; k < N_NODES / 4; k += 13 * 256)
            p[k] = z;
        if (b == 32 && t < 64) flags[t] = 0;
    }
}

// ------------------------------------------- single-pass lookback scan
// Replaces scan_local + scan_bsum + scan_add (3 dispatches -> 1).
// 49 blocks <= 64, so ONE 64-lane window covers all predecessors: lane t
// reads flag/agg of block b-1-t simultaneously (no serial chain). All
// cross-block communication via device-scope atomics + threadfence
// (per-XCD L2s are not coherent — plain stores are NOT safe, G16).
// flags: 0=invalid, 1=aggregate ready, 2=inclusive prefix ready.
__global__ __launch_bounds__(256) void scan_lookback(const int* __restrict__ counts,
                                                     int* __restrict__ offs,
                                                     int* __restrict__ aggv,
                                                     int* __restrict__ prefv,
                                                     int* __restrict__ flags, int n) {
    __shared__ int part[256];
    __shared__ int sh_exc;
    const int b = blockIdx.x, t = threadIdx.x;
    const int base = b * SCAN_CHUNK + t * 4;
    int v[4];
#pragma unroll
    for (int j = 0; j < 4; j++) {
        int idx = base + j;
        v[j] = (idx < n) ? counts[idx] : 0;
    }
    int s0 = v[0], s1 = s0 + v[1], s2 = s1 + v[2], s3 = s2 + v[3];
    part[t] = s3;
    __syncthreads();
    for (int off = 1; off < 256; off <<= 1) {
        int x = (t >= off) ? part[t - off] : 0;
        __syncthreads();
        part[t] += x;
        __syncthreads();
    }
    const int total = part[255];

    if (t == 0) {                       // publish block aggregate
        atomicExch(&aggv[b], total);
        __threadfence();
        atomicExch(&flags[b], 1);
    }
    if (t < 64) {                       // wave-parallel lookback (wave 0)
        int p = b - 1 - t;
        int f = 2, a = 0;
        if (p >= 0) {
            do { f = atomicAdd(&flags[p], 0); } while (f == 0);
            a = (f == 2) ? atomicAdd(&prefv[p], 0) : atomicAdd(&aggv[p], 0);
        }
        unsigned long long m = __ballot(f == 2);
        int t2 = __ffsll((long long)m) - 1;       // nearest prefix-ready cut
        int contrib = (t <= t2) ? a : 0;          // aggs below cut + prefix at cut
        for (int off = 32; off; off >>= 1) contrib += __shfl_down(contrib, off);
        if (t == 0) {
            atomicExch(&prefv[b], contrib + total);   // inclusive prefix
            __threadfence();
            atomicExch(&flags[b], 2);
            sh_exc = contrib;                          // exclusive prefix
        }
    }
    __syncthreads();
    const int prefix = sh_exc + ((t > 0) ? part[t - 1] : 0);
    int e[4] = {prefix, prefix + s0, prefix + s1, prefix + s2};
#pragma unroll
    for (int j = 0; j < 4; j++) {
        int idx = base + j;
        if (idx < n) offs[idx] = e[j];
    }
    if (b == (int)gridDim.x - 1 && t == 255) offs[n] = sh_exc + total;
}

// atomic-free scatter: rank captured during the (single) atomic hist pass
__global__ __launch_bounds__(256) void scatter_kernel(const int* __restrict__ src,
                                                      const int* __restrict__ dst,
                                                      const int* __restrict__ offs,
                                                      const int* __restrict__ rank,
                                                      int* __restrict__ csr_src, int E) {
    int i = blockIdx.x * blockDim.x + threadIdx.x;
    if (i < E) {
        int d = dst[i];
        csr_src[offs[d] + rank[i]] = src[i];
    }
}

// -------------------------------------------- fp16 MFMA GEMM + fused el/er
// v10 (unchanged from R13): rank-capturing hist after the last K-step
// (R11: vmcnt is in-order; atomics before a barrier serialize in front of
// the GEMM). v8 core: double-buffered LDS, global_load_lds staging (step
// k+1 issued before consuming step k), swizzle via pre-permuted GLOBAL
// source slot + swizzled read. Layer-1 A (fp32) reg-staged
// load-early/cvt-late. BM=64, 782 blocks, 512 thr / 8 waves, 32x64/wave.
template <int A32, int DO_HIST>
__global__ __launch_bounds__(512) void mfma_gemm(const _Float16* __restrict__ A16,
                                                 const float* __restrict__ Af,
                                                 const _Float16* __restrict__ Bt,
                                                 const float* __restrict__ al,
                                                 const float* __restrict__ ar,
                                                 _Float16* __restrict__ feat16,
                                                 float* __restrict__ el,
                                                 float* __restrict__ er,
                                                 const int* __restrict__ dst,
                                                 int* __restrict__ counts,
                                                 int* __restrict__ rank) {
    __shared__ _Float16 ash[2][64 * 32];    // 2 x 4 KB
    __shared__ _Float16 bsh[2][256 * 32];   // 2 x 16 KB

    const int t = threadIdx.x;
    const int m0 = blockIdx.x * 64;
    const int wave = t >> 6, lane = t & 63;
    const int quad = lane >> 4, l16 = lane & 15;
    const int wr = (wave >> 2) * 32;     // rowband: 0 or 32
    const int wc = (wave & 3) * 64;      // colband: 0/64/128/192 (== head*64)

    // ---- A reg-staging geometry (A32 path): thread -> one float4 of the tile
    const int arow = t >> 3, aq4 = t & 7;                  // 64 rows x 8 slots
    const int agr = (m0 + arow < N_NODES) ? m0 + arow : N_NODES - 1;
    const int aswz = (aq4 >> 1) ^ (arow & 3) ^ ((arow >> 2) & 3);
    const int aoff = arow * 32 + aswz * 8 + (aq4 & 1) * 4; // halves

    const f32x4 zero = {0.f, 0.f, 0.f, 0.f};
    f32x4 acc[2][4];
#pragma unroll
    for (int i = 0; i < 2; i++)
#pragma unroll
        for (int j = 0; j < 4; j++) acc[i][j] = zero;

    const int rslot = (quad ^ (l16 & 3) ^ (l16 >> 2)) * 8;   // read slot (halves)

    float4 areg;

    // ---------------- prologue: stage step 0 into buffer 0
    if (A32) {
        const float* p = &Af[(size_t)agr * FDIM + aq4 * 4];
        float4 f0 = *(const float4*)p;
        half4 hv = {(_Float16)f0.x, (_Float16)f0.y, (_Float16)f0.z, (_Float16)f0.w};
        *(half4*)&ash[0][aoff] = hv;
    } else {
        if (wave < 4) {
            int u = wave * 64 + lane;
            int row = u >> 2, sl = u & 3;
            int ss = sl ^ (row & 3) ^ ((row >> 2) & 3);
            int gr = (m0 + row < N_NODES) ? m0 + row : N_NODES - 1;
            gload_lds16(&A16[(size_t)gr * FDIM + ss * 8], &ash[0][u * 8]);
        }
    }
#pragma unroll
    for (int ii = 0; ii < 2; ii++) {
        int u = (wave * 2 + ii) * 64 + lane;
        int row = u >> 2, sl = u & 3;
        int ss = sl ^ (row & 3) ^ ((row >> 2) & 3);
        gload_lds16(&Bt[(size_t)row * FDIM + ss * 8], &bsh[0][u * 8]);
    }
    __syncthreads();

    // ---------------- main loop: 8 K-steps, one barrier each
    for (int ks = 0; ks < 8; ks++) {
        const int cur = ks & 1, nxt = cur ^ 1;
        const int kk2 = (ks + 1) * 32;
        const bool pf = (ks < 7);

        // ---- issue prefetch for step ks+1 (fire-and-forget until barrier)
        if (pf) {
            if (A32) {
                areg = *(const float4*)&Af[(size_t)agr * FDIM + kk2 + aq4 * 4];
            } else {
                if (wave < 4) {
                    int u = wave * 64 + lane;
                    int row = u >> 2, sl = u & 3;
                    int ss = sl ^ (row & 3) ^ ((row >> 2) & 3);
                    int gr = (m0 + row < N_NODES) ? m0 + row : N_NODES - 1;
                    gload_lds16(&A16[(size_t)gr * FDIM + kk2 + ss * 8], &ash[nxt][u * 8]);
                }
            }
#pragma unroll
            for (int ii = 0; ii < 2; ii++) {
                int u = (wave * 2 + ii) * 64 + lane;
                int row = u >> 2, sl = u & 3;
                int ss = sl ^ (row & 3) ^ ((row >> 2) & 3);
                gload_lds16(&Bt[(size_t)row * FDIM + kk2 + ss * 8], &bsh[nxt][u * 8]);
            }
        }

        // ---- consume current buffer
        half8 af[2], bf[4];
#pragma unroll
        for (int i = 0; i < 2; i++)
            af[i] = *(half8*)&ash[cur][(wr + i * 16 + l16) * 32 + rslot];
#pragma unroll
        for (int i = 0; i < 4; i++)
            bf[i] = *(half8*)&bsh[cur][(wc + i * 16 + l16) * 32 + rslot];

        // swapped operands: C fragment transposed (l16 = m-row, quad*4+r = n-col)
#pragma unroll
        for (int mt = 0; mt < 2; mt++)
#pragma unroll
            for (int nt = 0; nt < 4; nt++)
                acc[mt][nt] = __builtin_amdgcn_mfma_f32_16x16x32_f16(bf[nt], af[mt], acc[mt][nt], 0, 0, 0);

        // ---- late half of the A32 prefetch: cvt + LDS write (waits its loads)
        if (A32 && pf) {
            half4 hv = {(_Float16)areg.x, (_Float16)areg.y, (_Float16)areg.z, (_Float16)areg.w};
            *(half4*)&ash[nxt][aoff] = hv;
        }
        if (pf) __syncthreads();   // drains gload_lds + ds_writes: next buffer ready
    }

    // ---- rank-capturing histogram (AFTER all barriers): the atomicAdd
    // return value is the edge's within-dst-segment rank; scatter needs no
    // atomics. Atomics + rank stores drain under the epilogue/kernel-end.
    if (DO_HIST) {
        for (int i = blockIdx.x * 512 + t; i < N_EDGES; i += gridDim.x * 512)
            rank[i] = atomicAdd(&counts[dst[i]], 1);
    }

    // ---- epilogue: vector feat16 store + fused el/er (this wave's head = h)
    const int h = wc >> 6;
    float4 alv[4], arv[4];
#pragma unroll
    for (int nt = 0; nt < 4; nt++) {
        alv[nt] = *(const float4*)&al[wc + nt * 16 + quad * 4];
        arv[nt] = *(const float4*)&ar[wc + nt * 16 + quad * 4];
    }
#pragma unroll
    for (int mt = 0; mt < 2; mt++) {
        const int m = m0 + wr + mt * 16 + l16;
        const bool ok = (m < N_NODES);
        float pl = 0.f, pr = 0.f;
#pragma unroll
        for (int nt = 0; nt < 4; nt++) {
            f32x4 v = acc[mt][nt];
            if (ok) {
                half4 hv = {(_Float16)v[0], (_Float16)v[1], (_Float16)v[2], (_Float16)v[3]};
                *(half4*)&feat16[(size_t)m * FDIM + wc + nt * 16 + quad * 4] = hv;
            }
            pl += v[0] * alv[nt].x + v[1] * alv[nt].y + v[2] * alv[nt].z + v[3] * alv[nt].w;
            pr += v[0] * arv[nt].x + v[1] * arv[nt].y + v[2] * arv[nt].z + v[3] * arv[nt].w;
        }
        pl += __shfl_xor(pl, 16);
        pl += __shfl_xor(pl, 32);
        pr += __shfl_xor(pr, 16);
        pr += __shfl_xor(pr, 32);
        if (quad == 0 && ok) {
            el[m * 4 + h] = pl;
            er[m * 4 + h] = pr;
        }
    }
}

// ------------------------------------------- fused softmax + aggregate
// Wave per node, NO LDS / NO barriers. Lane owns features f=lane*4..+3
// (head = lane>>4). v2: cooperative weights; MAC via __shfl broadcast,
// 4-wide. L3-traffic-bound (~199MB beyond-L2 @ ~3.9TB/s) — invariant to
// scheduling (R2/R3 ablations). Single-pass softmax.
// mode 0: write h1 as fp16 (layer-2 GEMM input); mode 1: fp32 head-major.
__global__ __launch_bounds__(256) void agg_fused(const _Float16* __restrict__ feat16,
                                                 const float* __restrict__ el,
                                                 const float* __restrict__ er,
                                                 const float* __restrict__ bias,
                                                 const int* __restrict__ offs,
                                                 const int* __restrict__ csr_src,
                                                 float* __restrict__ out,
                                                 _Float16* __restrict__ h1,
                                                 int mode) {
    const int wave = threadIdx.x >> 6;
    const int lane = threadIdx.x & 63;
    const int n = blockIdx.x * 4 + wave;
    const int head = lane >> 4;
    const int f = lane * 4;           // == head*64 + (lane&15)*4
    const int base16 = lane & 48;     // first lane of this head's 16-group
    const int j16 = lane & 15;
    const int beg = offs[n];
    const int end = offs[n + 1];
    const float er_h = er[n * 4 + head];

    float4 acc = make_float4(0.f, 0.f, 0.f, 0.f);
    float ss = 0.f;

    for (int c = beg; c < end; c += 16) {
        int e = c + j16;
        int s_own = 0;
        float w_own = 0.f;
        if (e < end) {
            s_own = csr_src[e];
            float lg = el[s_own * 4 + head] + er_h;
            lg = (lg > 0.f) ? lg : 0.2f * lg;
            w_own = __expf(lg);
        }
        ss += w_own;

        int rem = end - c;
        if (rem > 16) rem = 16;

        int j = 0;
        for (; j + 3 < rem; j += 4) {
            int s0 = __shfl(s_own, base16 + j);
            int s1 = __shfl(s_own, base16 + j + 1);
            int s2 = __shfl(s_own, base16 + j + 2);
            int s3 = __shfl(s_own, base16 + j + 3);
            float w0 = __shfl(w_own, base16 + j);
            float w1 = __shfl(w_own, base16 + j + 1);
            float w2 = __shfl(w_own, base16 + j + 2);
            float w3 = __shfl(w_own, base16 + j + 3);
            half4 v0 = *(const half4*)&feat16[(size_t)s0 * FDIM + f];
            half4 v1 = *(const half4*)&feat16[(size_t)s1 * FDIM + f];
            half4 v2 = *(const half4*)&feat16[(size_t)s2 * FDIM + f];
            half4 v3 = *(const half4*)&feat16[(size_t)s3 * FDIM + f];
            acc.x += w0 * (float)v0[0] + w1 * (float)v1[0];
            acc.y += w0 * (float)v0[1] + w1 * (float)v1[1];
            acc.z += w0 * (float)v0[2] + w1 * (float)v1[2];
            acc.w += w0 * (float)v0[3] + w1 * (float)v1[3];
            acc.x += w2 * (float)v2[0] + w3 * (float)v3[0];
            acc.y += w2 * (float)v2[1] + w3 * (float)v3[1];
            acc.z += w2 * (float)v2[2] + w3 * (float)v3[2];
            acc.w += w2 * (float)v2[3] + w3 * (float)v3[3];
        }
        for (; j < rem; j++) {
            int s0 = __shfl(s_own, base16 + j);
            float w0 = __shfl(w_own, base16 + j);
            half4 v0 = *(const half4*)&feat16[(size_t)s0 * FDIM + f];
            acc.x += w0 * (float)v0[0];
            acc.y += w0 * (float)v0[1];
            acc.z += w0 * (float)v0[2];
            acc.w += w0 * (float)v0[3];
        }
    }

    ss += __shfl_xor(ss, 1, 16);
    ss += __shfl_xor(ss, 2, 16);
    ss += __shfl_xor(ss, 4, 16);
    ss += __shfl_xor(ss, 8, 16);

    float S = fmaxf(ss, 1e-9f);
    float inv = 1.f / S;
    float4 bv = *(const float4*)&bias[f];
    float r0 = acc.x * inv + bv.x;
    float r1 = acc.y * inv + bv.y;
    float r2 = acc.z * inv + bv.z;
    float r3 = acc.w * inv + bv.w;
    r0 = (r0 > 0.f) ? r0 : expm1f(r0);
    r1 = (r1 > 0.f) ? r1 : expm1f(r1);
    r2 = (r2 > 0.f) ? r2 : expm1f(r2);
    r3 = (r3 > 0.f) ? r3 : expm1f(r3);

    if (mode) {
        const int d = (lane & 15) * 4;
        float4 rv = make_float4(r0, r1, r2, r3);
        *(float4*)&out[(size_t)head * N_NODES * HID + (size_t)n * HID + d] = rv;
    } else {
        half4 hv = {(_Float16)r0, (_Float16)r1, (_Float16)r2, (_Float16)r3};
        *(half4*)&h1[(size_t)n * FDIM + f] = hv;
    }
}

// ---------------------------------------------------------------- launch

extern "C" void kernel_launch(void* const* d_in, const int* in_sizes, int n_in,
                              void* d_out, int out_size, void* d_ws, size_t ws_size,
                              hipStream_t stream) {
    const float* x   = (const float*)d_in[0];
    const int*   src = (const int*)d_in[1];
    const int*   dst = (const int*)d_in[2];
    const float* W0  = (const float*)d_in[3];
    const float* al0 = (const float*)d_in[4];
    const float* ar0 = (const float*)d_in[5];
    const float* b0  = (const float*)d_in[6];
    const float* W1  = (const float*)d_in[7];
    const float* al1 = (const float*)d_in[8];
    const float* ar1 = (const float*)d_in[9];
    const float* b1  = (const float*)d_in[10];
    float* out = (float*)d_out;

    // h1 (layer-1 hidden, fp16) lives in the first 25.6 MB of d_out.
    _Float16* h1 = (_Float16*)d_out;

    // workspace layout
    _Float16* feat16 = (_Float16*)d_ws;                          // N*256 fp16
    _Float16* wt0 = feat16 + (size_t)N_NODES * FDIM;             // 256*256
    _Float16* wt1 = wt0 + FDIM * FDIM;                           // 256*256
    float* el    = (float*)(wt1 + FDIM * FDIM);                  // N*4
    float* er    = el + N_NODES * HEADS;                         // N*4
    int* counts  = (int*)(er + N_NODES * HEADS);                 // N
    int* offs    = counts + N_NODES;                             // N+1 (pad 50016)
    int* aggv    = offs + 50016;                                 // 64
    int* prefv   = aggv + 64;                                    // 64
    int* flags   = prefv + 64;                                   // 64
    int* csr_src = flags + 64;                                   // E
    int* rank    = csr_src + N_EDGES;                            // E

    const int ggrid = (N_NODES + 63) / 64;   // 782

    // ---- prep (wcast + zero counts/flags, 1 dispatch)
    prep_kernel<<<45, 256, 0, stream>>>(W0, W1, wt0, wt1, counts, flags);

    // ---- layer-1 GEMM + rank-capturing histogram (A from fp32 x)
    mfma_gemm<1, 1><<<ggrid, 512, 0, stream>>>(nullptr, x, wt0, al0, ar0,
                                               feat16, el, er, dst, counts, rank);

    // ---- single-pass scan + atomic-free scatter
    scan_lookback<<<SCAN_NB, 256, 0, stream>>>(counts, offs, aggv, prefv, flags, N_NODES);
    scatter_kernel<<<(N_EDGES + 255) / 256, 256, 0, stream>>>(src, dst, offs, rank, csr_src, N_EDGES);

    // ---- layer 1 aggregate (h1 fp16 written into d_out)
    agg_fused<<<N_NODES / 4, 256, 0, stream>>>(feat16, el, er, b0, offs, csr_src,
                                               out, h1, 0);

    // ---- layer 2 (reads h1 fp16; final head-major fp32 write to d_out)
    mfma_gemm<0, 0><<<ggrid, 512, 0, stream>>>(h1, nullptr, wt1, al1, ar1,
                                               feat16, el, er, nullptr, nullptr, nullptr);
    agg_fused<<<N_NODES / 4, 256, 0, stream>>>(feat16, el, er, b1, offs, csr_src,
                                               out, h1, 1);
}